// Round 7
// baseline (304.228 us; speedup 1.0000x reference)
//
#include <hip/hip_runtime.h>

#define N_NODES 100000
#define E_EDGES 50000
#define NNZ_CNT 1600000
#define C_IN 128
#define H_OUT 256
#define BKT 128                 // edges per bucket
#define NB 391                  // ceil(E_EDGES / BKT)
#define RPB 4096                // records per binning block

typedef __attribute__((ext_vector_type(8))) short short8;   // 8 bf16 = 4 VGPR
typedef __attribute__((ext_vector_type(4))) float f32x4;    // MFMA accumulator

// RNE float->bf16
__device__ __forceinline__ ushort f2b(float f) {
  union { float f; uint u; } v; v.f = f;
  return (ushort)((v.u + 0x7FFFu + ((v.u >> 16) & 1u)) >> 16);
}
__device__ __forceinline__ float b2f(ushort u) {
  union { uint u; float f; } v; v.u = ((uint)u) << 16;
  return v.f;
}

// ---------------------------------------------------------------------------
// Kernel 1: y/batch_0 -> out (f32); convert x -> bf16. (chist zeroed by
// hipMemsetAsync in kernel_launch.)
// ---------------------------------------------------------------------------
__global__ __launch_bounds__(256) void init_kernel(
    const float* __restrict__ x, const int* __restrict__ y,
    const int* __restrict__ batch0, ushort* __restrict__ xb,
    float* __restrict__ out, int nconv4) {
  int i = blockIdx.x * 256 + threadIdx.x;
  if (i < nconv4) {
    float4 v = ((const float4*)x)[i];
    ushort4 u;
    u.x = f2b(v.x); u.y = f2b(v.y); u.z = f2b(v.z); u.w = f2b(v.w);
    ((ushort4*)xb)[i] = u;
  }
  if (i < N_NODES) {
    out[i]           = (float)y[i];
    out[N_NODES + i] = (float)batch0[i];
  }
}

// ---------------------------------------------------------------------------
// Kernel 2: coarse histogram (bucket = row>>7) via LDS hist + merged atomics
// ---------------------------------------------------------------------------
__global__ __launch_bounds__(256) void histc_kernel(
    const int* __restrict__ rows, int* __restrict__ chist) {
  __shared__ int h[NB];
  int t = threadIdx.x;
  for (int b = t; b < NB; b += 256) h[b] = 0;
  __syncthreads();
  int i0 = blockIdx.x * RPB;
  for (int k = 0; k < RPB / 256; ++k) {
    int i = i0 + k * 256 + t;
    if (i < NNZ_CNT) atomicAdd(&h[rows[i] >> 7], 1);
  }
  __syncthreads();
  for (int b = t; b < NB; b += 256)
    if (h[b]) atomicAdd(&chist[b], h[b]);
}

// ---------------------------------------------------------------------------
// Kernel 3: scan of chist[NB] -> boff[NB+1], gtail[NB]; seed eoff tail.
// ---------------------------------------------------------------------------
__global__ __launch_bounds__(512) void scanc_kernel(
    const int* __restrict__ chist, int* __restrict__ boff,
    int* __restrict__ gtail, int* __restrict__ eoff) {
  __shared__ int s[512];
  int t = threadIdx.x;
  int v = (t < NB) ? chist[t] : 0;
  s[t] = v;
  __syncthreads();
  for (int d = 1; d < 512; d <<= 1) {
    int u = (t >= d) ? s[t - d] : 0;
    __syncthreads();
    s[t] += u;
    __syncthreads();
  }
  if (t < NB) {
    int ex = s[t] - v;
    boff[t]  = ex;
    gtail[t] = ex;
  }
  if (t == 0) { boff[NB] = NNZ_CNT; eoff[NB * BKT] = NNZ_CNT; }
}

// ---------------------------------------------------------------------------
// Kernel 4: bin records bucket-clustered into buf:
//   buf[pos] = { (row&127)<<17 | col , bits(val) }
// rows cached in registers between the two passes (saves a 6.4MB re-read).
// ---------------------------------------------------------------------------
__global__ __launch_bounds__(256) void binpass_kernel(
    const int* __restrict__ rows, const int* __restrict__ cols,
    const float* __restrict__ vals, int* __restrict__ gtail,
    uint2* __restrict__ buf) {
  __shared__ int hist[NB], rnk[NB], base[NB];
  int rcache[RPB / 256];
  int t = threadIdx.x;
  for (int b = t; b < NB; b += 256) { hist[b] = 0; rnk[b] = 0; }
  __syncthreads();
  int i0 = blockIdx.x * RPB;
#pragma unroll
  for (int k = 0; k < RPB / 256; ++k) {
    int i = i0 + k * 256 + t;
    int r = (i < NNZ_CNT) ? rows[i] : -1;
    rcache[k] = r;
    if (r >= 0) atomicAdd(&hist[r >> 7], 1);
  }
  __syncthreads();
  for (int b = t; b < NB; b += 256) {
    int c = hist[b];
    base[b] = c ? atomicAdd(&gtail[b], c) : 0;
  }
  __syncthreads();
#pragma unroll
  for (int k = 0; k < RPB / 256; ++k) {
    int r = rcache[k];
    if (r >= 0) {
      int i = i0 + k * 256 + t;
      int b = r >> 7;
      int pos = base[b] + atomicAdd(&rnk[b], 1);
      buf[pos] = make_uint2(((uint)(r & (BKT - 1)) << 17) | (uint)cols[i],
                            __float_as_uint(vals[i]));
    }
  }
}

// ---------------------------------------------------------------------------
// Kernel 5: fine regroup within each bucket: exact per-edge CSR (L2-local).
// ---------------------------------------------------------------------------
__global__ __launch_bounds__(256) void finepass_kernel(
    const uint2* __restrict__ buf, const int* __restrict__ boff,
    uint2* __restrict__ buf2, int* __restrict__ eoff) {
  __shared__ int lhist[BKT], lexc[BKT], lrnk[BKT];
  int t = threadIdx.x;
  int b = blockIdx.x;
  if (t < BKT) { lhist[t] = 0; lrnk[t] = 0; }
  __syncthreads();
  int start = boff[b], end = boff[b + 1];
  for (int i = start + t; i < end; i += 256)
    atomicAdd(&lhist[buf[i].x >> 17], 1);
  __syncthreads();
  if (t < BKT) lexc[t] = lhist[t];
  __syncthreads();
  for (int d = 1; d < BKT; d <<= 1) {           // Hillis-Steele inclusive
    int v = (t < BKT && t >= d) ? lexc[t - d] : 0;
    __syncthreads();
    if (t < BKT) lexc[t] += v;
    __syncthreads();
  }
  if (t < BKT) {
    int ex = lexc[t] - lhist[t];                // -> exclusive
    lexc[t] = ex;
    eoff[b * BKT + t] = start + ex;
  }
  __syncthreads();
  for (int i = start + t; i < end; i += 256) {
    uint2 rec = buf[i];
    int rl = rec.x >> 17;
    int r = atomicAdd(&lrnk[rl], 1);
    buf2[start + lexc[rl] + r] = rec;
  }
}

// ---------------------------------------------------------------------------
// Kernel 6: per-edge gather-reduce, wave-per-edge. Lane owns channels
// 2*lane, 2*lane+1 (ushort2: whole 256B row in ONE wave transaction).
// Record read buf2[j] is wave-uniform (scalarizable, L2-hot, contiguous).
// ---------------------------------------------------------------------------
__global__ __launch_bounds__(256) void edge_reduce(
    const ushort* __restrict__ xb, const uint2* __restrict__ buf2,
    const int* __restrict__ eoff, ushort* __restrict__ x1b) {
  int wave = threadIdx.x >> 6, lane = threadIdx.x & 63;
  int e = blockIdx.x * 4 + wave;
  if (e >= E_EDGES) return;
  int start = eoff[e], end = eoff[e + 1];
  float a0 = 0.f, a1 = 0.f;
  for (int j = start; j < end; ++j) {
    uint2 rec = buf2[j];                        // wave-uniform
    float v = __uint_as_float(rec.y);
    ushort2 xv = *(const ushort2*)(xb + (size_t)(rec.x & 0x1FFFFu) * C_IN +
                                   2 * lane);
    a0 = fmaf(b2f(xv.x), v, a0);
    a1 = fmaf(b2f(xv.y), v, a1);
  }
  uint lo = f2b(a0), hi = f2b(a1);
  ((uint*)x1b)[(size_t)e * 64 + lane] = lo | (hi << 16);
}

// ---------------------------------------------------------------------------
// Kernel 7: pack W (f32 [128,256]) into per-fragment bf16 layout (verified)
// ---------------------------------------------------------------------------
__global__ __launch_bounds__(256) void wprep_kernel(
    const float* __restrict__ W0, const float* __restrict__ W1,
    ushort* __restrict__ Wf) {
  int idx = blockIdx.x * 256 + threadIdx.x;  // 0..8191
  if (idx >= 8192) return;
  const float* W = (idx & 4096) ? W1 : W0;
  int slot = idx & 4095;
  int nt = slot >> 8, ks = (slot >> 6) & 3, lane = slot & 63;
  int c  = nt * 16 + (lane & 15);
  int kb = ks * 32 + ((lane >> 4) << 3);
  short8 v;
#pragma unroll
  for (int j = 0; j < 8; ++j) v[j] = (short)f2b(W[(kb + j) * H_OUT + c]);
  ((short8*)Wf)[idx] = v;
}

// ---------------------------------------------------------------------------
// Kernel 8: merged MFMA GEMMs: relu(A @ W + b). Body verified round 3.
// Blocks [0,nb0) -> {A0,W slot 0,b0,out0,M=N}; rest -> {A1,W slot 1,b1,out1,E}.
// ---------------------------------------------------------------------------
__device__ __forceinline__ void gemm_body(
    const ushort* __restrict__ A, const ushort* __restrict__ Wf,
    const float* __restrict__ bias, float* __restrict__ out, int M, int bid) {
  int wave = threadIdx.x >> 6;
  int lane = threadIdx.x & 63;
  int wm = wave >> 1, wn = wave & 1;
  int r0 = bid * 64 + wm * 32;

  int arow = lane & 15;
  int kgrp = lane >> 4;

  short8 a[2][4];
#pragma unroll
  for (int mt = 0; mt < 2; ++mt) {
    int row = min(r0 + mt * 16 + arow, M - 1);
    const ushort* ap = A + (size_t)row * C_IN + kgrp * 8;
#pragma unroll
    for (int ks = 0; ks < 4; ++ks)
      a[mt][ks] = *(const short8*)(ap + ks * 32);
  }

  f32x4 acc[2][8];
#pragma unroll
  for (int mt = 0; mt < 2; ++mt)
#pragma unroll
    for (int nt = 0; nt < 8; ++nt) acc[mt][nt] = (f32x4){0.f, 0.f, 0.f, 0.f};

#pragma unroll
  for (int nt = 0; nt < 8; ++nt) {
    int gnt = wn * 8 + nt;
    const short8* bp = (const short8*)Wf + (size_t)(gnt * 4) * 64 + lane;
#pragma unroll
    for (int ks = 0; ks < 4; ++ks) {
      short8 bfrag = bp[(size_t)ks * 64];
      acc[0][nt] = __builtin_amdgcn_mfma_f32_16x16x32_bf16(a[0][ks], bfrag, acc[0][nt], 0, 0, 0);
      acc[1][nt] = __builtin_amdgcn_mfma_f32_16x16x32_bf16(a[1][ks], bfrag, acc[1][nt], 0, 0, 0);
    }
  }

  int crow = kgrp * 4;
  int ccol = lane & 15;
#pragma unroll
  for (int mt = 0; mt < 2; ++mt) {
#pragma unroll
    for (int nt = 0; nt < 8; ++nt) {
      int col = wn * 128 + nt * 16 + ccol;
      float bb = bias[col];
#pragma unroll
      for (int reg = 0; reg < 4; ++reg) {
        int row = r0 + mt * 16 + crow + reg;
        if (row < M)
          out[(size_t)row * H_OUT + col] = fmaxf(acc[mt][nt][reg] + bb, 0.f);
      }
    }
  }
}

__global__ __launch_bounds__(256) void gemm_dual(
    const ushort* __restrict__ A0, const ushort* __restrict__ A1,
    const ushort* __restrict__ Wf, const float* __restrict__ bias0,
    const float* __restrict__ bias1, float* __restrict__ out0,
    float* __restrict__ out1, int nb0) {
  int bid = blockIdx.x;
  if (bid < nb0)
    gemm_body(A0, Wf, bias0, out0, N_NODES, bid);
  else
    gemm_body(A1, Wf + 8 * 4096, bias1, out1, E_EDGES, bid - nb0);
}

// ---------------------------------------------------------------------------
extern "C" void kernel_launch(void* const* d_in, const int* in_sizes, int n_in,
                              void* d_out, int out_size, void* d_ws, size_t ws_size,
                              hipStream_t stream) {
  const float* x        = (const float*)d_in[0];
  const int*   inc_rows = (const int*)d_in[1];
  const int*   inc_cols = (const int*)d_in[2];
  const float* inc_vals = (const float*)d_in[3];
  const int*   y        = (const int*)d_in[4];
  const int*   batch0   = (const int*)d_in[5];
  const float* W0       = (const float*)d_in[6];
  const float* b0       = (const float*)d_in[7];
  const float* W1       = (const float*)d_in[8];
  const float* b1       = (const float*)d_in[9];

  float* out = (float*)d_out;

  // ws: xb 25.6MB | x1b 12.8MB | buf 12.8MB | buf2 12.8MB | Wf 128KB |
  //     chist/boff/gtail ~5KB | eoff 200KB   (~65MB total)
  char* ws = (char*)d_ws;
  ushort* xb    = (ushort*)ws;  ws += (size_t)N_NODES * C_IN * 2;
  ushort* x1b   = (ushort*)ws;  ws += (size_t)E_EDGES * C_IN * 2;
  uint2*  buf   = (uint2*)ws;   ws += (size_t)NNZ_CNT * 8;
  uint2*  buf2  = (uint2*)ws;   ws += (size_t)NNZ_CNT * 8;
  ushort* Wf    = (ushort*)ws;  ws += (size_t)8192 * 8 * 2;
  int*    chist = (int*)ws;     ws += (size_t)NB * 4;
  int*    boff  = (int*)ws;     ws += (size_t)(NB + 1) * 4;
  int*    gtail = (int*)ws;     ws += (size_t)NB * 4;
  int*    eoff  = (int*)ws;     // NB*BKT+1 ints

  const int nconv4 = N_NODES * C_IN / 4;         // 3.2M
  const int nbin   = (NNZ_CNT + RPB - 1) / RPB;  // 391
  const int nb0    = (N_NODES + 63) / 64;        // 1563
  const int nb1    = (E_EDGES + 63) / 64;        // 782

  wprep_kernel<<<32, 256, 0, stream>>>(W0, W1, Wf);
  hipMemsetAsync(chist, 0, (size_t)NB * 4, stream);
  init_kernel<<<(nconv4 + 255) / 256, 256, 0, stream>>>(x, y, batch0, xb, out,
                                                        nconv4);
  histc_kernel<<<nbin, 256, 0, stream>>>(inc_rows, chist);
  scanc_kernel<<<1, 512, 0, stream>>>(chist, boff, gtail, eoff);
  binpass_kernel<<<nbin, 256, 0, stream>>>(inc_rows, inc_cols, inc_vals,
                                           gtail, buf);
  finepass_kernel<<<NB, 256, 0, stream>>>(buf, boff, buf2, eoff);
  edge_reduce<<<(E_EDGES + 3) / 4, 256, 0, stream>>>(xb, buf2, eoff, x1b);

  float* x0_out = out + 2 * N_NODES;
  float* x1_out = out + 2 * N_NODES + (size_t)N_NODES * H_OUT;

  gemm_dual<<<nb0 + nb1, 256, 0, stream>>>(xb, x1b, Wf, b0, b1,
                                           x0_out, x1_out, nb0);
}

// Round 8
// 249.974 us; speedup vs baseline: 1.2170x; 1.2170x over previous
//
#include <hip/hip_runtime.h>

#define N_NODES 100000
#define E_EDGES 50000
#define NNZ_CNT 1600000
#define C_IN 128
#define H_OUT 256
#define BKT 128                 // edges per bucket
#define NB 391                  // ceil(E_EDGES / BKT)
#define RPB 4096                // records per binning block

typedef __attribute__((ext_vector_type(8))) short short8;   // 8 bf16 = 4 VGPR
typedef __attribute__((ext_vector_type(4))) float f32x4;    // MFMA accumulator

// RNE float->bf16
__device__ __forceinline__ ushort f2b(float f) {
  union { float f; uint u; } v; v.f = f;
  return (ushort)((v.u + 0x7FFFu + ((v.u >> 16) & 1u)) >> 16);
}
__device__ __forceinline__ float b2f(ushort u) {
  union { uint u; float f; } v; v.u = ((uint)u) << 16;
  return v.f;
}

// ---------------------------------------------------------------------------
// Kernel 1: y/batch_0 -> out (f32); convert x -> bf16. (chist zeroed by
// hipMemsetAsync in kernel_launch.)
// ---------------------------------------------------------------------------
__global__ __launch_bounds__(256) void init_kernel(
    const float* __restrict__ x, const int* __restrict__ y,
    const int* __restrict__ batch0, ushort* __restrict__ xb,
    float* __restrict__ out, int nconv4) {
  int i = blockIdx.x * 256 + threadIdx.x;
  if (i < nconv4) {
    float4 v = ((const float4*)x)[i];
    ushort4 u;
    u.x = f2b(v.x); u.y = f2b(v.y); u.z = f2b(v.z); u.w = f2b(v.w);
    ((ushort4*)xb)[i] = u;
  }
  if (i < N_NODES) {
    out[i]           = (float)y[i];
    out[N_NODES + i] = (float)batch0[i];
  }
}

// ---------------------------------------------------------------------------
// Kernel 2: coarse histogram (bucket = row>>7) via LDS hist + merged atomics
// ---------------------------------------------------------------------------
__global__ __launch_bounds__(256) void histc_kernel(
    const int* __restrict__ rows, int* __restrict__ chist) {
  __shared__ int h[NB];
  int t = threadIdx.x;
  for (int b = t; b < NB; b += 256) h[b] = 0;
  __syncthreads();
  int i0 = blockIdx.x * RPB;
  for (int k = 0; k < RPB / 256; ++k) {
    int i = i0 + k * 256 + t;
    if (i < NNZ_CNT) atomicAdd(&h[rows[i] >> 7], 1);
  }
  __syncthreads();
  for (int b = t; b < NB; b += 256)
    if (h[b]) atomicAdd(&chist[b], h[b]);
}

// ---------------------------------------------------------------------------
// Kernel 3: scan of chist[NB] -> boff[NB+1], gtail[NB]; seed eoff tail.
// ---------------------------------------------------------------------------
__global__ __launch_bounds__(512) void scanc_kernel(
    const int* __restrict__ chist, int* __restrict__ boff,
    int* __restrict__ gtail, int* __restrict__ eoff) {
  __shared__ int s[512];
  int t = threadIdx.x;
  int v = (t < NB) ? chist[t] : 0;
  s[t] = v;
  __syncthreads();
  for (int d = 1; d < 512; d <<= 1) {
    int u = (t >= d) ? s[t - d] : 0;
    __syncthreads();
    s[t] += u;
    __syncthreads();
  }
  if (t < NB) {
    int ex = s[t] - v;
    boff[t]  = ex;
    gtail[t] = ex;
  }
  if (t == 0) { boff[NB] = NNZ_CNT; eoff[NB * BKT] = NNZ_CNT; }
}

// ---------------------------------------------------------------------------
// Kernel 4: bin records bucket-clustered into buf:
//   buf[pos] = { (row&127)<<17 | col , bits(val) }
// rows cached in registers between the two passes (saves a 6.4MB re-read).
// ---------------------------------------------------------------------------
__global__ __launch_bounds__(256) void binpass_kernel(
    const int* __restrict__ rows, const int* __restrict__ cols,
    const float* __restrict__ vals, int* __restrict__ gtail,
    uint2* __restrict__ buf) {
  __shared__ int hist[NB], rnk[NB], base[NB];
  int rcache[RPB / 256];
  int t = threadIdx.x;
  for (int b = t; b < NB; b += 256) { hist[b] = 0; rnk[b] = 0; }
  __syncthreads();
  int i0 = blockIdx.x * RPB;
#pragma unroll
  for (int k = 0; k < RPB / 256; ++k) {
    int i = i0 + k * 256 + t;
    int r = (i < NNZ_CNT) ? rows[i] : -1;
    rcache[k] = r;
    if (r >= 0) atomicAdd(&hist[r >> 7], 1);
  }
  __syncthreads();
  for (int b = t; b < NB; b += 256) {
    int c = hist[b];
    base[b] = c ? atomicAdd(&gtail[b], c) : 0;
  }
  __syncthreads();
#pragma unroll
  for (int k = 0; k < RPB / 256; ++k) {
    int r = rcache[k];
    if (r >= 0) {
      int i = i0 + k * 256 + t;
      int b = r >> 7;
      int pos = base[b] + atomicAdd(&rnk[b], 1);
      buf[pos] = make_uint2(((uint)(r & (BKT - 1)) << 17) | (uint)cols[i],
                            __float_as_uint(vals[i]));
    }
  }
}

// ---------------------------------------------------------------------------
// Kernel 5: fine regroup within each bucket: exact per-edge CSR (L2-local).
// ---------------------------------------------------------------------------
__global__ __launch_bounds__(256) void finepass_kernel(
    const uint2* __restrict__ buf, const int* __restrict__ boff,
    uint2* __restrict__ buf2, int* __restrict__ eoff) {
  __shared__ int lhist[BKT], lexc[BKT], lrnk[BKT];
  int t = threadIdx.x;
  int b = blockIdx.x;
  if (t < BKT) { lhist[t] = 0; lrnk[t] = 0; }
  __syncthreads();
  int start = boff[b], end = boff[b + 1];
  for (int i = start + t; i < end; i += 256)
    atomicAdd(&lhist[buf[i].x >> 17], 1);
  __syncthreads();
  if (t < BKT) lexc[t] = lhist[t];
  __syncthreads();
  for (int d = 1; d < BKT; d <<= 1) {           // Hillis-Steele inclusive
    int v = (t < BKT && t >= d) ? lexc[t - d] : 0;
    __syncthreads();
    if (t < BKT) lexc[t] += v;
    __syncthreads();
  }
  if (t < BKT) {
    int ex = lexc[t] - lhist[t];                // -> exclusive
    lexc[t] = ex;
    eoff[b * BKT + t] = start + ex;
  }
  __syncthreads();
  for (int i = start + t; i < end; i += 256) {
    uint2 rec = buf[i];
    int rl = rec.x >> 17;
    int r = atomicAdd(&lrnk[rl], 1);
    buf2[start + lexc[rl] + r] = rec;
  }
}

// ---------------------------------------------------------------------------
// Kernel 6: per-edge gather-reduce. PROVEN r5 structure (block = 128 = 2
// waves per edge, meta staged in LDS, fixed 128-rec inner chunks for deep
// outstanding-load ILP) with one fix: waves split records (w, w+2, ...) and
// each lane owns channels {2l,2l+1} via ushort2 -> one full-width 256B
// transaction per record (r5 did 2x128B), half the vmem instructions.
// Cross-wave partials combined via LDS at the end.
// ---------------------------------------------------------------------------
__global__ __launch_bounds__(128) void edge_reduce(
    const ushort* __restrict__ xb, const uint2* __restrict__ buf2,
    const int* __restrict__ eoff, ushort* __restrict__ x1b) {
  __shared__ uint2 meta[128];
  __shared__ float pa[2][64], pb[2][64];
  int t = threadIdx.x, wave = t >> 6, lane = t & 63;
  int e = blockIdx.x;
  int start = eoff[e], end = eoff[e + 1];
  float a0 = 0.f, a1 = 0.f;
  for (int base = start; base < end; base += 128) {
    int m = min(128, end - base);
    if (t < m) meta[t] = buf2[base + t];
    __syncthreads();
    for (int j = wave; j < m; j += 2) {
      uint2 rec = meta[j];
      float v = __uint_as_float(rec.y);
      ushort2 xv = *(const ushort2*)(xb + (size_t)(rec.x & 0x1FFFFu) * C_IN +
                                     2 * lane);
      a0 = fmaf(b2f(xv.x), v, a0);
      a1 = fmaf(b2f(xv.y), v, a1);
    }
    __syncthreads();
  }
  pa[wave][lane] = a0;   // semantic channel 2*lane
  pb[wave][lane] = a1;   // semantic channel 2*lane+1
  __syncthreads();
  if (t < 64) {
    uint lo = f2b(pa[0][t] + pa[1][t]);
    uint hi = f2b(pb[0][t] + pb[1][t]);
    ((uint*)x1b)[(size_t)e * 64 + t] = lo | (hi << 16);
  }
}

// ---------------------------------------------------------------------------
// Kernel 7: pack W (f32 [128,256]) into per-fragment bf16 layout (verified)
// ---------------------------------------------------------------------------
__global__ __launch_bounds__(256) void wprep_kernel(
    const float* __restrict__ W0, const float* __restrict__ W1,
    ushort* __restrict__ Wf) {
  int idx = blockIdx.x * 256 + threadIdx.x;  // 0..8191
  if (idx >= 8192) return;
  const float* W = (idx & 4096) ? W1 : W0;
  int slot = idx & 4095;
  int nt = slot >> 8, ks = (slot >> 6) & 3, lane = slot & 63;
  int c  = nt * 16 + (lane & 15);
  int kb = ks * 32 + ((lane >> 4) << 3);
  short8 v;
#pragma unroll
  for (int j = 0; j < 8; ++j) v[j] = (short)f2b(W[(kb + j) * H_OUT + c]);
  ((short8*)Wf)[idx] = v;
}

// ---------------------------------------------------------------------------
// Kernel 8: merged MFMA GEMMs: relu(A @ W + b). Body verified round 3.
// ---------------------------------------------------------------------------
__device__ __forceinline__ void gemm_body(
    const ushort* __restrict__ A, const ushort* __restrict__ Wf,
    const float* __restrict__ bias, float* __restrict__ out, int M, int bid) {
  int wave = threadIdx.x >> 6;
  int lane = threadIdx.x & 63;
  int wm = wave >> 1, wn = wave & 1;
  int r0 = bid * 64 + wm * 32;

  int arow = lane & 15;
  int kgrp = lane >> 4;

  short8 a[2][4];
#pragma unroll
  for (int mt = 0; mt < 2; ++mt) {
    int row = min(r0 + mt * 16 + arow, M - 1);
    const ushort* ap = A + (size_t)row * C_IN + kgrp * 8;
#pragma unroll
    for (int ks = 0; ks < 4; ++ks)
      a[mt][ks] = *(const short8*)(ap + ks * 32);
  }

  f32x4 acc[2][8];
#pragma unroll
  for (int mt = 0; mt < 2; ++mt)
#pragma unroll
    for (int nt = 0; nt < 8; ++nt) acc[mt][nt] = (f32x4){0.f, 0.f, 0.f, 0.f};

#pragma unroll
  for (int nt = 0; nt < 8; ++nt) {
    int gnt = wn * 8 + nt;
    const short8* bp = (const short8*)Wf + (size_t)(gnt * 4) * 64 + lane;
#pragma unroll
    for (int ks = 0; ks < 4; ++ks) {
      short8 bfrag = bp[(size_t)ks * 64];
      acc[0][nt] = __builtin_amdgcn_mfma_f32_16x16x32_bf16(a[0][ks], bfrag, acc[0][nt], 0, 0, 0);
      acc[1][nt] = __builtin_amdgcn_mfma_f32_16x16x32_bf16(a[1][ks], bfrag, acc[1][nt], 0, 0, 0);
    }
  }

  int crow = kgrp * 4;
  int ccol = lane & 15;
#pragma unroll
  for (int mt = 0; mt < 2; ++mt) {
#pragma unroll
    for (int nt = 0; nt < 8; ++nt) {
      int col = wn * 128 + nt * 16 + ccol;
      float bb = bias[col];
#pragma unroll
      for (int reg = 0; reg < 4; ++reg) {
        int row = r0 + mt * 16 + crow + reg;
        if (row < M)
          out[(size_t)row * H_OUT + col] = fmaxf(acc[mt][nt][reg] + bb, 0.f);
      }
    }
  }
}

__global__ __launch_bounds__(256) void gemm_dual(
    const ushort* __restrict__ A0, const ushort* __restrict__ A1,
    const ushort* __restrict__ Wf, const float* __restrict__ bias0,
    const float* __restrict__ bias1, float* __restrict__ out0,
    float* __restrict__ out1, int nb0) {
  int bid = blockIdx.x;
  if (bid < nb0)
    gemm_body(A0, Wf, bias0, out0, N_NODES, bid);
  else
    gemm_body(A1, Wf + 8 * 4096, bias1, out1, E_EDGES, bid - nb0);
}

// ---------------------------------------------------------------------------
extern "C" void kernel_launch(void* const* d_in, const int* in_sizes, int n_in,
                              void* d_out, int out_size, void* d_ws, size_t ws_size,
                              hipStream_t stream) {
  const float* x        = (const float*)d_in[0];
  const int*   inc_rows = (const int*)d_in[1];
  const int*   inc_cols = (const int*)d_in[2];
  const float* inc_vals = (const float*)d_in[3];
  const int*   y        = (const int*)d_in[4];
  const int*   batch0   = (const int*)d_in[5];
  const float* W0       = (const float*)d_in[6];
  const float* b0       = (const float*)d_in[7];
  const float* W1       = (const float*)d_in[8];
  const float* b1       = (const float*)d_in[9];

  float* out = (float*)d_out;

  // ws: xb 25.6MB | x1b 12.8MB | buf 12.8MB | buf2 12.8MB | Wf 128KB |
  //     chist/boff/gtail ~5KB | eoff 200KB   (~65MB total)
  char* ws = (char*)d_ws;
  ushort* xb    = (ushort*)ws;  ws += (size_t)N_NODES * C_IN * 2;
  ushort* x1b   = (ushort*)ws;  ws += (size_t)E_EDGES * C_IN * 2;
  uint2*  buf   = (uint2*)ws;   ws += (size_t)NNZ_CNT * 8;
  uint2*  buf2  = (uint2*)ws;   ws += (size_t)NNZ_CNT * 8;
  ushort* Wf    = (ushort*)ws;  ws += (size_t)8192 * 8 * 2;
  int*    chist = (int*)ws;     ws += (size_t)NB * 4;
  int*    boff  = (int*)ws;     ws += (size_t)(NB + 1) * 4;
  int*    gtail = (int*)ws;     ws += (size_t)NB * 4;
  int*    eoff  = (int*)ws;     // NB*BKT+1 ints

  const int nconv4 = N_NODES * C_IN / 4;         // 3.2M
  const int nbin   = (NNZ_CNT + RPB - 1) / RPB;  // 391
  const int nb0    = (N_NODES + 63) / 64;        // 1563
  const int nb1    = (E_EDGES + 63) / 64;        // 782

  wprep_kernel<<<32, 256, 0, stream>>>(W0, W1, Wf);
  hipMemsetAsync(chist, 0, (size_t)NB * 4, stream);
  init_kernel<<<(nconv4 + 255) / 256, 256, 0, stream>>>(x, y, batch0, xb, out,
                                                        nconv4);
  histc_kernel<<<nbin, 256, 0, stream>>>(inc_rows, chist);
  scanc_kernel<<<1, 512, 0, stream>>>(chist, boff, gtail, eoff);
  binpass_kernel<<<nbin, 256, 0, stream>>>(inc_rows, inc_cols, inc_vals,
                                           gtail, buf);
  finepass_kernel<<<NB, 256, 0, stream>>>(buf, boff, buf2, eoff);
  edge_reduce<<<E_EDGES, 128, 0, stream>>>(xb, buf2, eoff, x1b);

  float* x0_out = out + 2 * N_NODES;
  float* x1_out = out + 2 * N_NODES + (size_t)N_NODES * H_OUT;

  gemm_dual<<<nb0 + nb1, 256, 0, stream>>>(xb, x1b, Wf, b0, b1,
                                           x0_out, x1_out, nb0);
}

// Round 9
// 216.692 us; speedup vs baseline: 1.4040x; 1.1536x over previous
//
#include <hip/hip_runtime.h>

#define N_NODES 100000
#define E_EDGES 50000
#define NNZ_CNT 1600000
#define C_IN 128
#define H_OUT 256
#define BKT 128                 // edges per bucket
#define NB 391                  // ceil(E_EDGES / BKT)
#define RPB 4096                // records per binning block

typedef __attribute__((ext_vector_type(8))) short short8;   // 8 bf16 = 4 VGPR
typedef __attribute__((ext_vector_type(4))) float f32x4;    // MFMA accumulator

// RNE float->bf16
__device__ __forceinline__ ushort f2b(float f) {
  union { float f; uint u; } v; v.f = f;
  return (ushort)((v.u + 0x7FFFu + ((v.u >> 16) & 1u)) >> 16);
}
__device__ __forceinline__ float b2f(ushort u) {
  union { uint u; float f; } v; v.u = ((uint)u) << 16;
  return v.f;
}

// ---------------------------------------------------------------------------
// Kernel 1: y/batch_0 -> out (f32); convert x -> bf16. (chist zeroed by
// hipMemsetAsync in kernel_launch.)
// ---------------------------------------------------------------------------
__global__ __launch_bounds__(256) void init_kernel(
    const float* __restrict__ x, const int* __restrict__ y,
    const int* __restrict__ batch0, ushort* __restrict__ xb,
    float* __restrict__ out, int nconv4) {
  int i = blockIdx.x * 256 + threadIdx.x;
  if (i < nconv4) {
    float4 v = ((const float4*)x)[i];
    ushort4 u;
    u.x = f2b(v.x); u.y = f2b(v.y); u.z = f2b(v.z); u.w = f2b(v.w);
    ((ushort4*)xb)[i] = u;
  }
  if (i < N_NODES) {
    out[i]           = (float)y[i];
    out[N_NODES + i] = (float)batch0[i];
  }
}

// ---------------------------------------------------------------------------
// Kernel 2: coarse histogram (bucket = row>>7) via LDS hist + merged atomics
// ---------------------------------------------------------------------------
__global__ __launch_bounds__(256) void histc_kernel(
    const int* __restrict__ rows, int* __restrict__ chist) {
  __shared__ int h[NB];
  int t = threadIdx.x;
  for (int b = t; b < NB; b += 256) h[b] = 0;
  __syncthreads();
  int i0 = blockIdx.x * RPB;
  for (int k = 0; k < RPB / 256; ++k) {
    int i = i0 + k * 256 + t;
    if (i < NNZ_CNT) atomicAdd(&h[rows[i] >> 7], 1);
  }
  __syncthreads();
  for (int b = t; b < NB; b += 256)
    if (h[b]) atomicAdd(&chist[b], h[b]);
}

// ---------------------------------------------------------------------------
// Kernel 3: scan of chist[NB] -> boff[NB+1], gtail[NB]; seed eoff tail.
// ---------------------------------------------------------------------------
__global__ __launch_bounds__(512) void scanc_kernel(
    const int* __restrict__ chist, int* __restrict__ boff,
    int* __restrict__ gtail, int* __restrict__ eoff) {
  __shared__ int s[512];
  int t = threadIdx.x;
  int v = (t < NB) ? chist[t] : 0;
  s[t] = v;
  __syncthreads();
  for (int d = 1; d < 512; d <<= 1) {
    int u = (t >= d) ? s[t - d] : 0;
    __syncthreads();
    s[t] += u;
    __syncthreads();
  }
  if (t < NB) {
    int ex = s[t] - v;
    boff[t]  = ex;
    gtail[t] = ex;
  }
  if (t == 0) { boff[NB] = NNZ_CNT; eoff[NB * BKT] = NNZ_CNT; }
}

// ---------------------------------------------------------------------------
// Kernel 4: bin records bucket-clustered into buf:
//   buf[pos] = { (row&127)<<17 | col , bits(val) }
// rows cached in registers between the two passes (saves a 6.4MB re-read).
// ---------------------------------------------------------------------------
__global__ __launch_bounds__(256) void binpass_kernel(
    const int* __restrict__ rows, const int* __restrict__ cols,
    const float* __restrict__ vals, int* __restrict__ gtail,
    uint2* __restrict__ buf) {
  __shared__ int hist[NB], rnk[NB], base[NB];
  int rcache[RPB / 256];
  int t = threadIdx.x;
  for (int b = t; b < NB; b += 256) { hist[b] = 0; rnk[b] = 0; }
  __syncthreads();
  int i0 = blockIdx.x * RPB;
#pragma unroll
  for (int k = 0; k < RPB / 256; ++k) {
    int i = i0 + k * 256 + t;
    int r = (i < NNZ_CNT) ? rows[i] : -1;
    rcache[k] = r;
    if (r >= 0) atomicAdd(&hist[r >> 7], 1);
  }
  __syncthreads();
  for (int b = t; b < NB; b += 256) {
    int c = hist[b];
    base[b] = c ? atomicAdd(&gtail[b], c) : 0;
  }
  __syncthreads();
#pragma unroll
  for (int k = 0; k < RPB / 256; ++k) {
    int r = rcache[k];
    if (r >= 0) {
      int i = i0 + k * 256 + t;
      int b = r >> 7;
      int pos = base[b] + atomicAdd(&rnk[b], 1);
      buf[pos] = make_uint2(((uint)(r & (BKT - 1)) << 17) | (uint)cols[i],
                            __float_as_uint(vals[i]));
    }
  }
}

// ---------------------------------------------------------------------------
// Kernel 5: fine regroup within each bucket: exact per-edge CSR (L2-local).
// buf2 records hold PRE-SCALED byte offsets: { col*256, bits(val) } — the
// reduce doesn't need rl (records are per-edge sorted via eoff).
// ---------------------------------------------------------------------------
__global__ __launch_bounds__(256) void finepass_kernel(
    const uint2* __restrict__ buf, const int* __restrict__ boff,
    uint2* __restrict__ buf2, int* __restrict__ eoff) {
  __shared__ int lhist[BKT], lexc[BKT], lrnk[BKT];
  int t = threadIdx.x;
  int b = blockIdx.x;
  if (t < BKT) { lhist[t] = 0; lrnk[t] = 0; }
  __syncthreads();
  int start = boff[b], end = boff[b + 1];
  for (int i = start + t; i < end; i += 256)
    atomicAdd(&lhist[buf[i].x >> 17], 1);
  __syncthreads();
  if (t < BKT) lexc[t] = lhist[t];
  __syncthreads();
  for (int d = 1; d < BKT; d <<= 1) {           // Hillis-Steele inclusive
    int v = (t < BKT && t >= d) ? lexc[t - d] : 0;
    __syncthreads();
    if (t < BKT) lexc[t] += v;
    __syncthreads();
  }
  if (t < BKT) {
    int ex = lexc[t] - lhist[t];                // -> exclusive
    lexc[t] = ex;
    eoff[b * BKT + t] = start + ex;
  }
  __syncthreads();
  for (int i = start + t; i < end; i += 256) {
    uint2 rec = buf[i];
    int rl = rec.x >> 17;
    int r = atomicAdd(&lrnk[rl], 1);
    buf2[start + lexc[rl] + r] =
        make_uint2((rec.x & 0x1FFFFu) << 8, rec.y);   // byte offset of row
  }
}

// ---------------------------------------------------------------------------
// Kernel 6: per-edge gather-reduce. r7-verified structure (block = 128 = 2
// waves per edge, meta staged in LDS, lane owns channels {2l,2l+1} via
// ushort2 = one full-width 256B transaction per record) + 4-way manual
// unroll with 2 independent accumulator pairs: 4 outstanding loads per wave
// to cover L3 latency (was ~1.6, the round-7 bottleneck).
// ---------------------------------------------------------------------------
__global__ __launch_bounds__(128) void edge_reduce(
    const ushort* __restrict__ xb, const uint2* __restrict__ buf2,
    const int* __restrict__ eoff, ushort* __restrict__ x1b) {
  __shared__ uint2 meta[128];
  __shared__ float pa[2][64], pb[2][64];
  int t = threadIdx.x, wave = t >> 6, lane = t & 63;
  int e = blockIdx.x;
  int start = eoff[e], end = eoff[e + 1];
  const char* xbase = (const char*)xb + 4 * lane;
  float s00 = 0.f, s01 = 0.f, s10 = 0.f, s11 = 0.f;
  for (int base = start; base < end; base += 128) {
    int m = min(128, end - base);
    if (t < m) meta[t] = buf2[base + t];
    __syncthreads();
    int j = wave;
    for (; j + 6 < m; j += 8) {
      uint2 r0 = meta[j], r1 = meta[j + 2], r2 = meta[j + 4], r3 = meta[j + 6];
      ushort2 v0 = *(const ushort2*)(xbase + r0.x);
      ushort2 v1 = *(const ushort2*)(xbase + r1.x);
      ushort2 v2 = *(const ushort2*)(xbase + r2.x);
      ushort2 v3 = *(const ushort2*)(xbase + r3.x);
      float w0 = __uint_as_float(r0.y), w1 = __uint_as_float(r1.y);
      float w2 = __uint_as_float(r2.y), w3 = __uint_as_float(r3.y);
      s00 = fmaf(b2f(v0.x), w0, s00); s01 = fmaf(b2f(v0.y), w0, s01);
      s10 = fmaf(b2f(v1.x), w1, s10); s11 = fmaf(b2f(v1.y), w1, s11);
      s00 = fmaf(b2f(v2.x), w2, s00); s01 = fmaf(b2f(v2.y), w2, s01);
      s10 = fmaf(b2f(v3.x), w3, s10); s11 = fmaf(b2f(v3.y), w3, s11);
    }
    for (; j < m; j += 2) {
      uint2 rec = meta[j];
      float w = __uint_as_float(rec.y);
      ushort2 xv = *(const ushort2*)(xbase + rec.x);
      s00 = fmaf(b2f(xv.x), w, s00);
      s01 = fmaf(b2f(xv.y), w, s01);
    }
    __syncthreads();
  }
  pa[wave][lane] = s00 + s10;   // semantic channel 2*lane
  pb[wave][lane] = s01 + s11;   // semantic channel 2*lane+1
  __syncthreads();
  if (t < 64) {
    uint lo = f2b(pa[0][t] + pa[1][t]);
    uint hi = f2b(pb[0][t] + pb[1][t]);
    ((uint*)x1b)[(size_t)e * 64 + t] = lo | (hi << 16);
  }
}

// ---------------------------------------------------------------------------
// Kernel 7: pack W (f32 [128,256]) into per-fragment bf16 layout (verified)
// ---------------------------------------------------------------------------
__global__ __launch_bounds__(256) void wprep_kernel(
    const float* __restrict__ W0, const float* __restrict__ W1,
    ushort* __restrict__ Wf) {
  int idx = blockIdx.x * 256 + threadIdx.x;  // 0..8191
  if (idx >= 8192) return;
  const float* W = (idx & 4096) ? W1 : W0;
  int slot = idx & 4095;
  int nt = slot >> 8, ks = (slot >> 6) & 3, lane = slot & 63;
  int c  = nt * 16 + (lane & 15);
  int kb = ks * 32 + ((lane >> 4) << 3);
  short8 v;
#pragma unroll
  for (int j = 0; j < 8; ++j) v[j] = (short)f2b(W[(kb + j) * H_OUT + c]);
  ((short8*)Wf)[idx] = v;
}

// ---------------------------------------------------------------------------
// Kernel 8: merged MFMA GEMMs: relu(A @ W + b). Body verified round 3.
// ---------------------------------------------------------------------------
__device__ __forceinline__ void gemm_body(
    const ushort* __restrict__ A, const ushort* __restrict__ Wf,
    const float* __restrict__ bias, float* __restrict__ out, int M, int bid) {
  int wave = threadIdx.x >> 6;
  int lane = threadIdx.x & 63;
  int wm = wave >> 1, wn = wave & 1;
  int r0 = bid * 64 + wm * 32;

  int arow = lane & 15;
  int kgrp = lane >> 4;

  short8 a[2][4];
#pragma unroll
  for (int mt = 0; mt < 2; ++mt) {
    int row = min(r0 + mt * 16 + arow, M - 1);
    const ushort* ap = A + (size_t)row * C_IN + kgrp * 8;
#pragma unroll
    for (int ks = 0; ks < 4; ++ks)
      a[mt][ks] = *(const short8*)(ap + ks * 32);
  }

  f32x4 acc[2][8];
#pragma unroll
  for (int mt = 0; mt < 2; ++mt)
#pragma unroll
    for (int nt = 0; nt < 8; ++nt) acc[mt][nt] = (f32x4){0.f, 0.f, 0.f, 0.f};

#pragma unroll
  for (int nt = 0; nt < 8; ++nt) {
    int gnt = wn * 8 + nt;
    const short8* bp = (const short8*)Wf + (size_t)(gnt * 4) * 64 + lane;
#pragma unroll
    for (int ks = 0; ks < 4; ++ks) {
      short8 bfrag = bp[(size_t)ks * 64];
      acc[0][nt] = __builtin_amdgcn_mfma_f32_16x16x32_bf16(a[0][ks], bfrag, acc[0][nt], 0, 0, 0);
      acc[1][nt] = __builtin_amdgcn_mfma_f32_16x16x32_bf16(a[1][ks], bfrag, acc[1][nt], 0, 0, 0);
    }
  }

  int crow = kgrp * 4;
  int ccol = lane & 15;
#pragma unroll
  for (int mt = 0; mt < 2; ++mt) {
#pragma unroll
    for (int nt = 0; nt < 8; ++nt) {
      int col = wn * 128 + nt * 16 + ccol;
      float bb = bias[col];
#pragma unroll
      for (int reg = 0; reg < 4; ++reg) {
        int row = r0 + mt * 16 + crow + reg;
        if (row < M)
          out[(size_t)row * H_OUT + col] = fmaxf(acc[mt][nt][reg] + bb, 0.f);
      }
    }
  }
}

__global__ __launch_bounds__(256) void gemm_dual(
    const ushort* __restrict__ A0, const ushort* __restrict__ A1,
    const ushort* __restrict__ Wf, const float* __restrict__ bias0,
    const float* __restrict__ bias1, float* __restrict__ out0,
    float* __restrict__ out1, int nb0) {
  int bid = blockIdx.x;
  if (bid < nb0)
    gemm_body(A0, Wf, bias0, out0, N_NODES, bid);
  else
    gemm_body(A1, Wf + 8 * 4096, bias1, out1, E_EDGES, bid - nb0);
}

// ---------------------------------------------------------------------------
extern "C" void kernel_launch(void* const* d_in, const int* in_sizes, int n_in,
                              void* d_out, int out_size, void* d_ws, size_t ws_size,
                              hipStream_t stream) {
  const float* x        = (const float*)d_in[0];
  const int*   inc_rows = (const int*)d_in[1];
  const int*   inc_cols = (const int*)d_in[2];
  const float* inc_vals = (const float*)d_in[3];
  const int*   y        = (const int*)d_in[4];
  const int*   batch0   = (const int*)d_in[5];
  const float* W0       = (const float*)d_in[6];
  const float* b0       = (const float*)d_in[7];
  const float* W1       = (const float*)d_in[8];
  const float* b1       = (const float*)d_in[9];

  float* out = (float*)d_out;

  // ws: xb 25.6MB | x1b 12.8MB | buf 12.8MB | buf2 12.8MB | Wf 128KB |
  //     chist/boff/gtail ~5KB | eoff 200KB   (~65MB total)
  char* ws = (char*)d_ws;
  ushort* xb    = (ushort*)ws;  ws += (size_t)N_NODES * C_IN * 2;
  ushort* x1b   = (ushort*)ws;  ws += (size_t)E_EDGES * C_IN * 2;
  uint2*  buf   = (uint2*)ws;   ws += (size_t)NNZ_CNT * 8;
  uint2*  buf2  = (uint2*)ws;   ws += (size_t)NNZ_CNT * 8;
  ushort* Wf    = (ushort*)ws;  ws += (size_t)8192 * 8 * 2;
  int*    chist = (int*)ws;     ws += (size_t)NB * 4;
  int*    boff  = (int*)ws;     ws += (size_t)(NB + 1) * 4;
  int*    gtail = (int*)ws;     ws += (size_t)NB * 4;
  int*    eoff  = (int*)ws;     // NB*BKT+1 ints

  const int nconv4 = N_NODES * C_IN / 4;         // 3.2M
  const int nbin   = (NNZ_CNT + RPB - 1) / RPB;  // 391
  const int nb0    = (N_NODES + 63) / 64;        // 1563
  const int nb1    = (E_EDGES + 63) / 64;        // 782

  wprep_kernel<<<32, 256, 0, stream>>>(W0, W1, Wf);
  hipMemsetAsync(chist, 0, (size_t)NB * 4, stream);
  init_kernel<<<(nconv4 + 255) / 256, 256, 0, stream>>>(x, y, batch0, xb, out,
                                                        nconv4);
  histc_kernel<<<nbin, 256, 0, stream>>>(inc_rows, chist);
  scanc_kernel<<<1, 512, 0, stream>>>(chist, boff, gtail, eoff);
  binpass_kernel<<<nbin, 256, 0, stream>>>(inc_rows, inc_cols, inc_vals,
                                           gtail, buf);
  finepass_kernel<<<NB, 256, 0, stream>>>(buf, boff, buf2, eoff);
  edge_reduce<<<E_EDGES, 128, 0, stream>>>(xb, buf2, eoff, x1b);

  float* x0_out = out + 2 * N_NODES;
  float* x1_out = out + 2 * N_NODES + (size_t)N_NODES * H_OUT;

  gemm_dual<<<nb0 + nb1, 256, 0, stream>>>(xb, x1b, Wf, b0, b1,
                                           x0_out, x1_out, nb0);
}

// Round 10
// 194.414 us; speedup vs baseline: 1.5648x; 1.1146x over previous
//
#include <hip/hip_runtime.h>

#define N_NODES 100000
#define E_EDGES 50000
#define NNZ_CNT 1600000
#define C_IN 128
#define H_OUT 256
#define BKT 128                 // edges per bucket
#define NB 391                  // ceil(E_EDGES / BKT)
#define RPB 4096                // records per binning block
#define NBIN 391                // ceil(NNZ_CNT / RPB)
#define GB_A 781                // gemm0 blocks fused into binpass dispatch
#define GB_B 782                // gemm0 blocks fused into finepass dispatch

typedef __attribute__((ext_vector_type(8))) short short8;   // 8 bf16 = 4 VGPR
typedef __attribute__((ext_vector_type(4))) float f32x4;    // MFMA accumulator

// RNE float->bf16
__device__ __forceinline__ ushort f2b(float f) {
  union { float f; uint u; } v; v.f = f;
  return (ushort)((v.u + 0x7FFFu + ((v.u >> 16) & 1u)) >> 16);
}
__device__ __forceinline__ float b2f(ushort u) {
  union { uint u; float f; } v; v.u = ((uint)u) << 16;
  return v.f;
}

// ---------------------------------------------------------------------------
// gemm body (verified r3): relu(A @ W + b), A:[M,128] bf16, Wf frag-packed.
// ---------------------------------------------------------------------------
__device__ __forceinline__ void gemm_body(
    const ushort* __restrict__ A, const ushort* __restrict__ Wf,
    const float* __restrict__ bias, float* __restrict__ out, int M, int bid) {
  int wave = threadIdx.x >> 6;
  int lane = threadIdx.x & 63;
  int wm = wave >> 1, wn = wave & 1;
  int r0 = bid * 64 + wm * 32;

  int arow = lane & 15;
  int kgrp = lane >> 4;

  short8 a[2][4];
#pragma unroll
  for (int mt = 0; mt < 2; ++mt) {
    int row = min(r0 + mt * 16 + arow, M - 1);
    const ushort* ap = A + (size_t)row * C_IN + kgrp * 8;
#pragma unroll
    for (int ks = 0; ks < 4; ++ks)
      a[mt][ks] = *(const short8*)(ap + ks * 32);
  }

  f32x4 acc[2][8];
#pragma unroll
  for (int mt = 0; mt < 2; ++mt)
#pragma unroll
    for (int nt = 0; nt < 8; ++nt) acc[mt][nt] = (f32x4){0.f, 0.f, 0.f, 0.f};

#pragma unroll
  for (int nt = 0; nt < 8; ++nt) {
    int gnt = wn * 8 + nt;
    const short8* bp = (const short8*)Wf + (size_t)(gnt * 4) * 64 + lane;
#pragma unroll
    for (int ks = 0; ks < 4; ++ks) {
      short8 bfrag = bp[(size_t)ks * 64];
      acc[0][nt] = __builtin_amdgcn_mfma_f32_16x16x32_bf16(a[0][ks], bfrag, acc[0][nt], 0, 0, 0);
      acc[1][nt] = __builtin_amdgcn_mfma_f32_16x16x32_bf16(a[1][ks], bfrag, acc[1][nt], 0, 0, 0);
    }
  }

  int crow = kgrp * 4;
  int ccol = lane & 15;
#pragma unroll
  for (int mt = 0; mt < 2; ++mt) {
#pragma unroll
    for (int nt = 0; nt < 8; ++nt) {
      int col = wn * 128 + nt * 16 + ccol;
      float bb = bias[col];
#pragma unroll
      for (int reg = 0; reg < 4; ++reg) {
        int row = r0 + mt * 16 + crow + reg;
        if (row < M)
          out[(size_t)row * H_OUT + col] = fmaxf(acc[mt][nt][reg] + bb, 0.f);
      }
    }
  }
}

// ---------------------------------------------------------------------------
// Kernel 1: FUSED prep = histc | wprep | init (mutually independent).
// blocks [0,NBIN): coarse histogram; [NBIN,NBIN+32): W pack; rest: x->bf16
// conversion + y/batch_0 writes. chist zeroed by hipMemsetAsync before this.
// ---------------------------------------------------------------------------
__global__ __launch_bounds__(256) void fused_prep(
    const float* __restrict__ x, const int* __restrict__ y,
    const int* __restrict__ batch0, const int* __restrict__ rows,
    const float* __restrict__ W0, const float* __restrict__ W1,
    ushort* __restrict__ xb, float* __restrict__ out,
    int* __restrict__ chist, ushort* __restrict__ Wf, int nconv4) {
  __shared__ int h[NB];
  int bid = blockIdx.x;
  int t = threadIdx.x;
  if (bid < NBIN) {                       // ---- histc ----
    for (int b = t; b < NB; b += 256) h[b] = 0;
    __syncthreads();
    int i0 = bid * RPB;
    for (int k = 0; k < RPB / 256; ++k) {
      int i = i0 + k * 256 + t;
      if (i < NNZ_CNT) atomicAdd(&h[rows[i] >> 7], 1);
    }
    __syncthreads();
    for (int b = t; b < NB; b += 256)
      if (h[b]) atomicAdd(&chist[b], h[b]);
  } else if (bid < NBIN + 32) {           // ---- wprep ----
    int idx = (bid - NBIN) * 256 + t;     // 0..8191
    const float* W = (idx & 4096) ? W1 : W0;
    int slot = idx & 4095;
    int nt = slot >> 8, ks = (slot >> 6) & 3, lane = slot & 63;
    int c  = nt * 16 + (lane & 15);
    int kb = ks * 32 + ((lane >> 4) << 3);
    short8 v;
#pragma unroll
    for (int j = 0; j < 8; ++j) v[j] = (short)f2b(W[(kb + j) * H_OUT + c]);
    ((short8*)Wf)[idx] = v;
  } else {                                // ---- init ----
    int i = (bid - NBIN - 32) * 256 + t;
    if (i < nconv4) {
      float4 v = ((const float4*)x)[i];
      ushort4 u;
      u.x = f2b(v.x); u.y = f2b(v.y); u.z = f2b(v.z); u.w = f2b(v.w);
      ((ushort4*)xb)[i] = u;
    }
    if (i < N_NODES) {
      out[i]           = (float)y[i];
      out[N_NODES + i] = (float)batch0[i];
    }
  }
}

// ---------------------------------------------------------------------------
// Kernel 2: scan of chist[NB] -> boff[NB+1], gtail[NB]; seed eoff tail.
// ---------------------------------------------------------------------------
__global__ __launch_bounds__(512) void scanc_kernel(
    const int* __restrict__ chist, int* __restrict__ boff,
    int* __restrict__ gtail, int* __restrict__ eoff) {
  __shared__ int s[512];
  int t = threadIdx.x;
  int v = (t < NB) ? chist[t] : 0;
  s[t] = v;
  __syncthreads();
  for (int d = 1; d < 512; d <<= 1) {
    int u = (t >= d) ? s[t - d] : 0;
    __syncthreads();
    s[t] += u;
    __syncthreads();
  }
  if (t < NB) {
    int ex = s[t] - v;
    boff[t]  = ex;
    gtail[t] = ex;
  }
  if (t == 0) { boff[NB] = NNZ_CNT; eoff[NB * BKT] = NNZ_CNT; }
}

// ---------------------------------------------------------------------------
// binpass body (verified r8): bucket-clustered records, rcache reg reuse.
// ---------------------------------------------------------------------------
__device__ __forceinline__ void binpass_body(
    const int* __restrict__ rows, const int* __restrict__ cols,
    const float* __restrict__ vals, int* __restrict__ gtail,
    uint2* __restrict__ buf, int* hist, int* rnk, int* base, int bid) {
  int rcache[RPB / 256];
  int t = threadIdx.x;
  for (int b = t; b < NB; b += 256) { hist[b] = 0; rnk[b] = 0; }
  __syncthreads();
  int i0 = bid * RPB;
#pragma unroll
  for (int k = 0; k < RPB / 256; ++k) {
    int i = i0 + k * 256 + t;
    int r = (i < NNZ_CNT) ? rows[i] : -1;
    rcache[k] = r;
    if (r >= 0) atomicAdd(&hist[r >> 7], 1);
  }
  __syncthreads();
  for (int b = t; b < NB; b += 256) {
    int c = hist[b];
    base[b] = c ? atomicAdd(&gtail[b], c) : 0;
  }
  __syncthreads();
#pragma unroll
  for (int k = 0; k < RPB / 256; ++k) {
    int r = rcache[k];
    if (r >= 0) {
      int i = i0 + k * 256 + t;
      int b = r >> 7;
      int pos = base[b] + atomicAdd(&rnk[b], 1);
      buf[pos] = make_uint2(((uint)(r & (BKT - 1)) << 17) | (uint)cols[i],
                            __float_as_uint(vals[i]));
    }
  }
}

// Kernel 3: binpass blocks + first GB_A gemm0 blocks (independent, overlap)
__global__ __launch_bounds__(256) void binpass_gemmA(
    const int* __restrict__ rows, const int* __restrict__ cols,
    const float* __restrict__ vals, int* __restrict__ gtail,
    uint2* __restrict__ buf, const ushort* __restrict__ xb,
    const ushort* __restrict__ Wf, const float* __restrict__ bias0,
    float* __restrict__ out0) {
  __shared__ int hist[NB], rnk[NB], base[NB];
  int bid = blockIdx.x;
  if (bid < NB)
    binpass_body(rows, cols, vals, gtail, buf, hist, rnk, base, bid);
  else
    gemm_body(xb, Wf, bias0, out0, N_NODES, bid - NB);
}

// ---------------------------------------------------------------------------
// finepass body (verified r8): per-bucket exact per-edge CSR; buf2 records
// hold pre-scaled byte offsets { col*256, bits(val) }.
// ---------------------------------------------------------------------------
__device__ __forceinline__ void finepass_body(
    const uint2* __restrict__ buf, const int* __restrict__ boff,
    uint2* __restrict__ buf2, int* __restrict__ eoff,
    int* lhist, int* lexc, int* lrnk, int b) {
  int t = threadIdx.x;
  if (t < BKT) { lhist[t] = 0; lrnk[t] = 0; }
  __syncthreads();
  int start = boff[b], end = boff[b + 1];
  for (int i = start + t; i < end; i += 256)
    atomicAdd(&lhist[buf[i].x >> 17], 1);
  __syncthreads();
  if (t < BKT) lexc[t] = lhist[t];
  __syncthreads();
  for (int d = 1; d < BKT; d <<= 1) {           // Hillis-Steele inclusive
    int v = (t < BKT && t >= d) ? lexc[t - d] : 0;
    __syncthreads();
    if (t < BKT) lexc[t] += v;
    __syncthreads();
  }
  if (t < BKT) {
    int ex = lexc[t] - lhist[t];                // -> exclusive
    lexc[t] = ex;
    eoff[b * BKT + t] = start + ex;
  }
  __syncthreads();
  for (int i = start + t; i < end; i += 256) {
    uint2 rec = buf[i];
    int rl = rec.x >> 17;
    int r = atomicAdd(&lrnk[rl], 1);
    buf2[start + lexc[rl] + r] =
        make_uint2((rec.x & 0x1FFFFu) << 8, rec.y);   // byte offset of row
  }
}

// Kernel 4: finepass blocks + remaining GB_B gemm0 blocks
__global__ __launch_bounds__(256) void finepass_gemmB(
    const uint2* __restrict__ buf, const int* __restrict__ boff,
    uint2* __restrict__ buf2, int* __restrict__ eoff,
    const ushort* __restrict__ xb, const ushort* __restrict__ Wf,
    const float* __restrict__ bias0, float* __restrict__ out0) {
  __shared__ int lhist[BKT], lexc[BKT], lrnk[BKT];
  int bid = blockIdx.x;
  if (bid < NB)
    finepass_body(buf, boff, buf2, eoff, lhist, lexc, lrnk, bid);
  else
    gemm_body(xb, Wf, bias0, out0, N_NODES, GB_A + (bid - NB));
}

// ---------------------------------------------------------------------------
// Kernel 5: per-edge gather-reduce (verified r8: staged LDS meta, full-width
// ushort2 lanes, 4-way unroll / 2 independent accumulator pairs).
// ---------------------------------------------------------------------------
__global__ __launch_bounds__(128) void edge_reduce(
    const ushort* __restrict__ xb, const uint2* __restrict__ buf2,
    const int* __restrict__ eoff, ushort* __restrict__ x1b) {
  __shared__ uint2 meta[128];
  __shared__ float pa[2][64], pb[2][64];
  int t = threadIdx.x, wave = t >> 6, lane = t & 63;
  int e = blockIdx.x;
  int start = eoff[e], end = eoff[e + 1];
  const char* xbase = (const char*)xb + 4 * lane;
  float s00 = 0.f, s01 = 0.f, s10 = 0.f, s11 = 0.f;
  for (int base = start; base < end; base += 128) {
    int m = min(128, end - base);
    if (t < m) meta[t] = buf2[base + t];
    __syncthreads();
    int j = wave;
    for (; j + 6 < m; j += 8) {
      uint2 r0 = meta[j], r1 = meta[j + 2], r2 = meta[j + 4], r3 = meta[j + 6];
      ushort2 v0 = *(const ushort2*)(xbase + r0.x);
      ushort2 v1 = *(const ushort2*)(xbase + r1.x);
      ushort2 v2 = *(const ushort2*)(xbase + r2.x);
      ushort2 v3 = *(const ushort2*)(xbase + r3.x);
      float w0 = __uint_as_float(r0.y), w1 = __uint_as_float(r1.y);
      float w2 = __uint_as_float(r2.y), w3 = __uint_as_float(r3.y);
      s00 = fmaf(b2f(v0.x), w0, s00); s01 = fmaf(b2f(v0.y), w0, s01);
      s10 = fmaf(b2f(v1.x), w1, s10); s11 = fmaf(b2f(v1.y), w1, s11);
      s00 = fmaf(b2f(v2.x), w2, s00); s01 = fmaf(b2f(v2.y), w2, s01);
      s10 = fmaf(b2f(v3.x), w3, s10); s11 = fmaf(b2f(v3.y), w3, s11);
    }
    for (; j < m; j += 2) {
      uint2 rec = meta[j];
      float w = __uint_as_float(rec.y);
      ushort2 xv = *(const ushort2*)(xbase + rec.x);
      s00 = fmaf(b2f(xv.x), w, s00);
      s01 = fmaf(b2f(xv.y), w, s01);
    }
    __syncthreads();
  }
  pa[wave][lane] = s00 + s10;   // semantic channel 2*lane
  pb[wave][lane] = s01 + s11;   // semantic channel 2*lane+1
  __syncthreads();
  if (t < 64) {
    uint lo = f2b(pa[0][t] + pa[1][t]);
    uint hi = f2b(pb[0][t] + pb[1][t]);
    ((uint*)x1b)[(size_t)e * 64 + t] = lo | (hi << 16);
  }
}

// ---------------------------------------------------------------------------
// Kernel 6: gemm for x1 (after edge_reduce)
// ---------------------------------------------------------------------------
__global__ __launch_bounds__(256) void gemm1_kernel(
    const ushort* __restrict__ A1, const ushort* __restrict__ Wf,
    const float* __restrict__ bias1, float* __restrict__ out1) {
  gemm_body(A1, Wf + 8 * 4096, bias1, out1, E_EDGES, blockIdx.x);
}

// ---------------------------------------------------------------------------
extern "C" void kernel_launch(void* const* d_in, const int* in_sizes, int n_in,
                              void* d_out, int out_size, void* d_ws, size_t ws_size,
                              hipStream_t stream) {
  const float* x        = (const float*)d_in[0];
  const int*   inc_rows = (const int*)d_in[1];
  const int*   inc_cols = (const int*)d_in[2];
  const float* inc_vals = (const float*)d_in[3];
  const int*   y        = (const int*)d_in[4];
  const int*   batch0   = (const int*)d_in[5];
  const float* W0       = (const float*)d_in[6];
  const float* b0       = (const float*)d_in[7];
  const float* W1       = (const float*)d_in[8];
  const float* b1       = (const float*)d_in[9];

  float* out = (float*)d_out;

  // ws: xb 25.6MB | x1b 12.8MB | buf 12.8MB | buf2 12.8MB | Wf 128KB |
  //     chist/boff/gtail ~5KB | eoff 200KB   (~65MB total)
  char* ws = (char*)d_ws;
  ushort* xb    = (ushort*)ws;  ws += (size_t)N_NODES * C_IN * 2;
  ushort* x1b   = (ushort*)ws;  ws += (size_t)E_EDGES * C_IN * 2;
  uint2*  buf   = (uint2*)ws;   ws += (size_t)NNZ_CNT * 8;
  uint2*  buf2  = (uint2*)ws;   ws += (size_t)NNZ_CNT * 8;
  ushort* Wf    = (ushort*)ws;  ws += (size_t)8192 * 8 * 2;
  int*    chist = (int*)ws;     ws += (size_t)NB * 4;
  int*    boff  = (int*)ws;     ws += (size_t)(NB + 1) * 4;
  int*    gtail = (int*)ws;     ws += (size_t)NB * 4;
  int*    eoff  = (int*)ws;     // NB*BKT+1 ints

  const int nconv4 = N_NODES * C_IN / 4;         // 3.2M
  const int ninit  = (nconv4 + 255) / 256;       // 12500
  const int nb1    = (E_EDGES + 63) / 64;        // 782

  float* x0_out = out + 2 * N_NODES;
  float* x1_out = out + 2 * N_NODES + (size_t)N_NODES * H_OUT;

  hipMemsetAsync(chist, 0, (size_t)NB * 4, stream);
  fused_prep<<<NBIN + 32 + ninit, 256, 0, stream>>>(
      x, y, batch0, inc_rows, W0, W1, xb, out, chist, Wf, nconv4);
  scanc_kernel<<<1, 512, 0, stream>>>(chist, boff, gtail, eoff);
  binpass_gemmA<<<NB + GB_A, 256, 0, stream>>>(
      inc_rows, inc_cols, inc_vals, gtail, buf, xb, Wf, b0, x0_out);
  finepass_gemmB<<<NB + GB_B, 256, 0, stream>>>(
      buf, boff, buf2, eoff, xb, Wf, b0, x0_out);
  edge_reduce<<<E_EDGES, 128, 0, stream>>>(xb, buf2, eoff, x1b);
  gemm1_kernel<<<nb1, 256, 0, stream>>>(x1b, Wf, b1, x1_out);
}

// Round 13
// 193.274 us; speedup vs baseline: 1.5741x; 1.0059x over previous
//
#include <hip/hip_runtime.h>

#define N_NODES 100000
#define E_EDGES 50000
#define NNZ_CNT 1600000
#define C_IN 128
#define H_OUT 256
#define BKT 128                 // edges per bucket
#define NB 391                  // ceil(E_EDGES / BKT)
#define RPB 4096                // records per binning block
#define NBIN 391                // ceil(NNZ_CNT / RPB)
#define GB_A 781                // gemm0 blocks fused into binpass dispatch
#define GB_B 782                // gemm0 blocks fused into finepass dispatch

typedef __attribute__((ext_vector_type(8))) short short8;   // 8 bf16 = 4 VGPR
typedef __attribute__((ext_vector_type(4))) float f32x4;    // MFMA accumulator

// RNE float->bf16
__device__ __forceinline__ ushort f2b(float f) {
  union { float f; uint u; } v; v.f = f;
  return (ushort)((v.u + 0x7FFFu + ((v.u >> 16) & 1u)) >> 16);
}
__device__ __forceinline__ float b2f(ushort u) {
  union { uint u; float f; } v; v.u = ((uint)u) << 16;
  return v.f;
}

// ---------------------------------------------------------------------------
// gemm body (verified r3): 64-row tile, 4 waves (2x2). relu(A @ W + b).
// ---------------------------------------------------------------------------
__device__ __forceinline__ void gemm_body(
    const ushort* __restrict__ A, const ushort* __restrict__ Wf,
    const float* __restrict__ bias, float* __restrict__ out, int M, int bid) {
  int wave = threadIdx.x >> 6;
  int lane = threadIdx.x & 63;
  int wm = wave >> 1, wn = wave & 1;
  int r0 = bid * 64 + wm * 32;

  int arow = lane & 15;
  int kgrp = lane >> 4;

  short8 a[2][4];
#pragma unroll
  for (int mt = 0; mt < 2; ++mt) {
    int row = min(r0 + mt * 16 + arow, M - 1);
    const ushort* ap = A + (size_t)row * C_IN + kgrp * 8;
#pragma unroll
    for (int ks = 0; ks < 4; ++ks)
      a[mt][ks] = *(const short8*)(ap + ks * 32);
  }

  f32x4 acc[2][8];
#pragma unroll
  for (int mt = 0; mt < 2; ++mt)
#pragma unroll
    for (int nt = 0; nt < 8; ++nt) acc[mt][nt] = (f32x4){0.f, 0.f, 0.f, 0.f};

#pragma unroll
  for (int nt = 0; nt < 8; ++nt) {
    int gnt = wn * 8 + nt;
    const short8* bp = (const short8*)Wf + (size_t)(gnt * 4) * 64 + lane;
#pragma unroll
    for (int ks = 0; ks < 4; ++ks) {
      short8 bfrag = bp[(size_t)ks * 64];
      acc[0][nt] = __builtin_amdgcn_mfma_f32_16x16x32_bf16(a[0][ks], bfrag, acc[0][nt], 0, 0, 0);
      acc[1][nt] = __builtin_amdgcn_mfma_f32_16x16x32_bf16(a[1][ks], bfrag, acc[1][nt], 0, 0, 0);
    }
  }

  int crow = kgrp * 4;
  int ccol = lane & 15;
#pragma unroll
  for (int mt = 0; mt < 2; ++mt) {
#pragma unroll
    for (int nt = 0; nt < 8; ++nt) {
      int col = wn * 128 + nt * 16 + ccol;
      float bb = bias[col];
#pragma unroll
      for (int reg = 0; reg < 4; ++reg) {
        int row = r0 + mt * 16 + crow + reg;
        if (row < M)
          out[(size_t)row * H_OUT + col] = fmaxf(acc[mt][nt][reg] + bb, 0.f);
      }
    }
  }
}

// ---------------------------------------------------------------------------
// Kernel 1: FUSED prep = histc | wprep | init (mutually independent).
// chist zeroed by hipMemsetAsync before this.
// ---------------------------------------------------------------------------
__global__ __launch_bounds__(256) void fused_prep(
    const float* __restrict__ x, const int* __restrict__ y,
    const int* __restrict__ batch0, const int* __restrict__ rows,
    const float* __restrict__ W0, const float* __restrict__ W1,
    ushort* __restrict__ xb, float* __restrict__ out,
    int* __restrict__ chist, ushort* __restrict__ Wf, int nconv4) {
  __shared__ int h[NB];
  int bid = blockIdx.x;
  int t = threadIdx.x;
  if (bid < NBIN) {                       // ---- histc ----
    for (int b = t; b < NB; b += 256) h[b] = 0;
    __syncthreads();
    int i0 = bid * RPB;
    for (int k = 0; k < RPB / 256; ++k) {
      int i = i0 + k * 256 + t;
      if (i < NNZ_CNT) atomicAdd(&h[rows[i] >> 7], 1);
    }
    __syncthreads();
    for (int b = t; b < NB; b += 256)
      if (h[b]) atomicAdd(&chist[b], h[b]);
  } else if (bid < NBIN + 32) {           // ---- wprep ----
    int idx = (bid - NBIN) * 256 + t;     // 0..8191
    const float* W = (idx & 4096) ? W1 : W0;
    int slot = idx & 4095;
    int nt = slot >> 8, ks = (slot >> 6) & 3, lane = slot & 63;
    int c  = nt * 16 + (lane & 15);
    int kb = ks * 32 + ((lane >> 4) << 3);
    short8 v;
#pragma unroll
    for (int j = 0; j < 8; ++j) v[j] = (short)f2b(W[(kb + j) * H_OUT + c]);
    ((short8*)Wf)[idx] = v;
  } else {                                // ---- init ----
    int i = (bid - NBIN - 32) * 256 + t;
    if (i < nconv4) {
      float4 v = ((const float4*)x)[i];
      ushort4 u;
      u.x = f2b(v.x); u.y = f2b(v.y); u.z = f2b(v.z); u.w = f2b(v.w);
      ((ushort4*)xb)[i] = u;
    }
    if (i < N_NODES) {
      out[i]           = (float)y[i];
      out[N_NODES + i] = (float)batch0[i];
    }
  }
}

// ---------------------------------------------------------------------------
// Kernel 2: scan of chist[NB] -> boff[NB+1], gtail[NB]; seed eoff tail.
// ---------------------------------------------------------------------------
__global__ __launch_bounds__(512) void scanc_kernel(
    const int* __restrict__ chist, int* __restrict__ boff,
    int* __restrict__ gtail, int* __restrict__ eoff) {
  __shared__ int s[512];
  int t = threadIdx.x;
  int v = (t < NB) ? chist[t] : 0;
  s[t] = v;
  __syncthreads();
  for (int d = 1; d < 512; d <<= 1) {
    int u = (t >= d) ? s[t - d] : 0;
    __syncthreads();
    s[t] += u;
    __syncthreads();
  }
  if (t < NB) {
    int ex = s[t] - v;
    boff[t]  = ex;
    gtail[t] = ex;
  }
  if (t == 0) { boff[NB] = NNZ_CNT; eoff[NB * BKT] = NNZ_CNT; }
}

// ---------------------------------------------------------------------------
// binpass body (verified r8): bucket-clustered records, rcache reg reuse.
// ---------------------------------------------------------------------------
__device__ __forceinline__ void binpass_body(
    const int* __restrict__ rows, const int* __restrict__ cols,
    const float* __restrict__ vals, int* __restrict__ gtail,
    uint2* __restrict__ buf, int* hist, int* rnk, int* base, int bid) {
  int rcache[RPB / 256];
  int t = threadIdx.x;
  for (int b = t; b < NB; b += 256) { hist[b] = 0; rnk[b] = 0; }
  __syncthreads();
  int i0 = bid * RPB;
#pragma unroll
  for (int k = 0; k < RPB / 256; ++k) {
    int i = i0 + k * 256 + t;
    int r = (i < NNZ_CNT) ? rows[i] : -1;
    rcache[k] = r;
    if (r >= 0) atomicAdd(&hist[r >> 7], 1);
  }
  __syncthreads();
  for (int b = t; b < NB; b += 256) {
    int c = hist[b];
    base[b] = c ? atomicAdd(&gtail[b], c) : 0;
  }
  __syncthreads();
#pragma unroll
  for (int k = 0; k < RPB / 256; ++k) {
    int r = rcache[k];
    if (r >= 0) {
      int i = i0 + k * 256 + t;
      int b = r >> 7;
      int pos = base[b] + atomicAdd(&rnk[b], 1);
      buf[pos] = make_uint2(((uint)(r & (BKT - 1)) << 17) | (uint)cols[i],
                            __float_as_uint(vals[i]));
    }
  }
}

// Kernel 3: binpass blocks + first GB_A gemm0 blocks (independent, overlap)
__global__ __launch_bounds__(256) void binpass_gemmA(
    const int* __restrict__ rows, const int* __restrict__ cols,
    const float* __restrict__ vals, int* __restrict__ gtail,
    uint2* __restrict__ buf, const ushort* __restrict__ xb,
    const ushort* __restrict__ Wf, const float* __restrict__ bias0,
    float* __restrict__ out0) {
  __shared__ int hist[NB], rnk[NB], base[NB];
  int bid = blockIdx.x;
  if (bid < NB)
    binpass_body(rows, cols, vals, gtail, buf, hist, rnk, base, bid);
  else
    gemm_body(xb, Wf, bias0, out0, N_NODES, bid - NB);
}

// ---------------------------------------------------------------------------
// finepass body (verified r8): per-bucket exact per-edge CSR; buf2 records
// hold pre-scaled byte offsets { col*256, bits(val) }.
// ---------------------------------------------------------------------------
__device__ __forceinline__ void finepass_body(
    const uint2* __restrict__ buf, const int* __restrict__ boff,
    uint2* __restrict__ buf2, int* __restrict__ eoff,
    int* lhist, int* lexc, int* lrnk, int b) {
  int t = threadIdx.x;
  if (t < BKT) { lhist[t] = 0; lrnk[t] = 0; }
  __syncthreads();
  int start = boff[b], end = boff[b + 1];
  for (int i = start + t; i < end; i += 256)
    atomicAdd(&lhist[buf[i].x >> 17], 1);
  __syncthreads();
  if (t < BKT) lexc[t] = lhist[t];
  __syncthreads();
  for (int d = 1; d < BKT; d <<= 1) {           // Hillis-Steele inclusive
    int v = (t < BKT && t >= d) ? lexc[t - d] : 0;
    __syncthreads();
    if (t < BKT) lexc[t] += v;
    __syncthreads();
  }
  if (t < BKT) {
    int ex = lexc[t] - lhist[t];                // -> exclusive
    lexc[t] = ex;
    eoff[b * BKT + t] = start + ex;
  }
  __syncthreads();
  for (int i = start + t; i < end; i += 256) {
    uint2 rec = buf[i];
    int rl = rec.x >> 17;
    int r = atomicAdd(&lrnk[rl], 1);
    buf2[start + lexc[rl] + r] =
        make_uint2((rec.x & 0x1FFFFu) << 8, rec.y);   // byte offset of row
  }
}

// Kernel 4: finepass blocks + remaining GB_B gemm0 blocks
__global__ __launch_bounds__(256) void finepass_gemmB(
    const uint2* __restrict__ buf, const int* __restrict__ boff,
    uint2* __restrict__ buf2, int* __restrict__ eoff,
    const ushort* __restrict__ xb, const ushort* __restrict__ Wf,
    const float* __restrict__ bias0, float* __restrict__ out0) {
  __shared__ int lhist[BKT], lexc[BKT], lrnk[BKT];
  int bid = blockIdx.x;
  if (bid < NB)
    finepass_body(buf, boff, buf2, eoff, lhist, lexc, lrnk, bid);
  else
    gemm_body(xb, Wf, bias0, out0, N_NODES, GB_A + (bid - NB));
}

// ---------------------------------------------------------------------------
// Kernel 5: per-edge gather-reduce (verified r8: staged LDS meta, full-width
// ushort2 lanes, 4-way unroll / 2 independent accumulator pairs).
// ---------------------------------------------------------------------------
__global__ __launch_bounds__(128) void edge_reduce(
    const ushort* __restrict__ xb, const uint2* __restrict__ buf2,
    const int* __restrict__ eoff, ushort* __restrict__ x1b) {
  __shared__ uint2 meta[128];
  __shared__ float pa[2][64], pb[2][64];
  int t = threadIdx.x, wave = t >> 6, lane = t & 63;
  int e = blockIdx.x;
  int start = eoff[e], end = eoff[e + 1];
  const char* xbase = (const char*)xb + 4 * lane;
  float s00 = 0.f, s01 = 0.f, s10 = 0.f, s11 = 0.f;
  for (int base = start; base < end; base += 128) {
    int m = min(128, end - base);
    if (t < m) meta[t] = buf2[base + t];
    __syncthreads();
    int j = wave;
    for (; j + 6 < m; j += 8) {
      uint2 r0 = meta[j], r1 = meta[j + 2], r2 = meta[j + 4], r3 = meta[j + 6];
      ushort2 v0 = *(const ushort2*)(xbase + r0.x);
      ushort2 v1 = *(const ushort2*)(xbase + r1.x);
      ushort2 v2 = *(const ushort2*)(xbase + r2.x);
      ushort2 v3 = *(const ushort2*)(xbase + r3.x);
      float w0 = __uint_as_float(r0.y), w1 = __uint_as_float(r1.y);
      float w2 = __uint_as_float(r2.y), w3 = __uint_as_float(r3.y);
      s00 = fmaf(b2f(v0.x), w0, s00); s01 = fmaf(b2f(v0.y), w0, s01);
      s10 = fmaf(b2f(v1.x), w1, s10); s11 = fmaf(b2f(v1.y), w1, s11);
      s00 = fmaf(b2f(v2.x), w2, s00); s01 = fmaf(b2f(v2.y), w2, s01);
      s10 = fmaf(b2f(v3.x), w3, s10); s11 = fmaf(b2f(v3.y), w3, s11);
    }
    for (; j < m; j += 2) {
      uint2 rec = meta[j];
      float w = __uint_as_float(rec.y);
      ushort2 xv = *(const ushort2*)(xbase + rec.x);
      s00 = fmaf(b2f(xv.x), w, s00);
      s01 = fmaf(b2f(xv.y), w, s01);
    }
    __syncthreads();
  }
  pa[wave][lane] = s00 + s10;   // semantic channel 2*lane
  pb[wave][lane] = s01 + s11;   // semantic channel 2*lane+1
  __syncthreads();
  if (t < 64) {
    uint lo = f2b(pa[0][t] + pa[1][t]);
    uint hi = f2b(pb[0][t] + pb[1][t]);
    ((uint*)x1b)[(size_t)e * 64 + t] = lo | (hi << 16);
  }
}

// ---------------------------------------------------------------------------
// Kernel 6: gemm for x1 (after edge_reduce)
// ---------------------------------------------------------------------------
__global__ __launch_bounds__(256) void gemm1_kernel(
    const ushort* __restrict__ A1, const ushort* __restrict__ Wf,
    const float* __restrict__ bias1, float* __restrict__ out1) {
  gemm_body(A1, Wf + 8 * 4096, bias1, out1, E_EDGES, blockIdx.x);
}

// ---------------------------------------------------------------------------
extern "C" void kernel_launch(void* const* d_in, const int* in_sizes, int n_in,
                              void* d_out, int out_size, void* d_ws, size_t ws_size,
                              hipStream_t stream) {
  const float* x        = (const float*)d_in[0];
  const int*   inc_rows = (const int*)d_in[1];
  const int*   inc_cols = (const int*)d_in[2];
  const float* inc_vals = (const float*)d_in[3];
  const int*   y        = (const int*)d_in[4];
  const int*   batch0   = (const int*)d_in[5];
  const float* W0       = (const float*)d_in[6];
  const float* b0       = (const float*)d_in[7];
  const float* W1       = (const float*)d_in[8];
  const float* b1       = (const float*)d_in[9];

  float* out = (float*)d_out;

  // ws: xb 25.6MB | x1b 12.8MB | buf 12.8MB | buf2 12.8MB | Wf 128KB |
  //     chist/boff/gtail ~5KB | eoff 200KB   (~65MB total)
  char* ws = (char*)d_ws;
  ushort* xb    = (ushort*)ws;  ws += (size_t)N_NODES * C_IN * 2;
  ushort* x1b   = (ushort*)ws;  ws += (size_t)E_EDGES * C_IN * 2;
  uint2*  buf   = (uint2*)ws;   ws += (size_t)NNZ_CNT * 8;
  uint2*  buf2  = (uint2*)ws;   ws += (size_t)NNZ_CNT * 8;
  ushort* Wf    = (ushort*)ws;  ws += (size_t)8192 * 8 * 2;
  int*    chist = (int*)ws;     ws += (size_t)NB * 4;
  int*    boff  = (int*)ws;     ws += (size_t)(NB + 1) * 4;
  int*    gtail = (int*)ws;     ws += (size_t)NB * 4;
  int*    eoff  = (int*)ws;     // NB*BKT+1 ints

  const int nconv4 = N_NODES * C_IN / 4;         // 3.2M
  const int ninit  = (nconv4 + 255) / 256;       // 12500
  const int nb1    = (E_EDGES + 63) / 64;        // 782

  float* x0_out = out + 2 * N_NODES;
  float* x1_out = out + 2 * N_NODES + (size_t)N_NODES * H_OUT;

  hipMemsetAsync(chist, 0, (size_t)NB * 4, stream);
  fused_prep<<<NBIN + 32 + ninit, 256, 0, stream>>>(
      x, y, batch0, inc_rows, W0, W1, xb, out, chist, Wf, nconv4);
  scanc_kernel<<<1, 512, 0, stream>>>(chist, boff, gtail, eoff);
  binpass_gemmA<<<NB + GB_A, 256, 0, stream>>>(
      inc_rows, inc_cols, inc_vals, gtail, buf, xb, Wf, b0, x0_out);
  finepass_gemmB<<<NB + GB_B, 256, 0, stream>>>(
      buf, boff, buf2, eoff, xb, Wf, b0, x0_out);
  edge_reduce<<<E_EDGES, 128, 0, stream>>>(xb, buf2, eoff, x1b);
  gemm1_kernel<<<nb1, 256, 0, stream>>>(x1b, Wf, b1, x1_out);
}

// Round 15
// 192.303 us; speedup vs baseline: 1.5820x; 1.0050x over previous
//
#include <hip/hip_runtime.h>

#define N_NODES 100000
#define E_EDGES 50000
#define NNZ_CNT 1600000
#define C_IN 128
#define H_OUT 256
#define BKT 128                 // edges per bucket
#define NB 391                  // ceil(E_EDGES / BKT)
#define RPB 4096                // records per binning block
#define NBIN 391                // ceil(NNZ_CNT / RPB)
#define GB_A 781                // gemm0 blocks fused into binpass dispatch
#define GB_B 782                // gemm0 blocks fused into finepass dispatch

typedef __attribute__((ext_vector_type(8))) short short8;   // 8 bf16 = 4 VGPR
typedef __attribute__((ext_vector_type(4))) float f32x4;    // MFMA accumulator

// RNE float->bf16
__device__ __forceinline__ ushort f2b(float f) {
  union { float f; uint u; } v; v.f = f;
  return (ushort)((v.u + 0x7FFFu + ((v.u >> 16) & 1u)) >> 16);
}
__device__ __forceinline__ float b2f(ushort u) {
  union { uint u; float f; } v; v.u = ((uint)u) << 16;
  return v.f;
}

// ---------------------------------------------------------------------------
// gemm body (verified r3): 64-row tile, 4 waves (2x2). relu(A @ W + b).
// ---------------------------------------------------------------------------
__device__ __forceinline__ void gemm_body(
    const ushort* __restrict__ A, const ushort* __restrict__ Wf,
    const float* __restrict__ bias, float* __restrict__ out, int M, int bid) {
  int wave = threadIdx.x >> 6;
  int lane = threadIdx.x & 63;
  int wm = wave >> 1, wn = wave & 1;
  int r0 = bid * 64 + wm * 32;

  int arow = lane & 15;
  int kgrp = lane >> 4;

  short8 a[2][4];
#pragma unroll
  for (int mt = 0; mt < 2; ++mt) {
    int row = min(r0 + mt * 16 + arow, M - 1);
    const ushort* ap = A + (size_t)row * C_IN + kgrp * 8;
#pragma unroll
    for (int ks = 0; ks < 4; ++ks)
      a[mt][ks] = *(const short8*)(ap + ks * 32);
  }

  f32x4 acc[2][8];
#pragma unroll
  for (int mt = 0; mt < 2; ++mt)
#pragma unroll
    for (int nt = 0; nt < 8; ++nt) acc[mt][nt] = (f32x4){0.f, 0.f, 0.f, 0.f};

#pragma unroll
  for (int nt = 0; nt < 8; ++nt) {
    int gnt = wn * 8 + nt;
    const short8* bp = (const short8*)Wf + (size_t)(gnt * 4) * 64 + lane;
#pragma unroll
    for (int ks = 0; ks < 4; ++ks) {
      short8 bfrag = bp[(size_t)ks * 64];
      acc[0][nt] = __builtin_amdgcn_mfma_f32_16x16x32_bf16(a[0][ks], bfrag, acc[0][nt], 0, 0, 0);
      acc[1][nt] = __builtin_amdgcn_mfma_f32_16x16x32_bf16(a[1][ks], bfrag, acc[1][nt], 0, 0, 0);
    }
  }

  int crow = kgrp * 4;
  int ccol = lane & 15;
#pragma unroll
  for (int mt = 0; mt < 2; ++mt) {
#pragma unroll
    for (int nt = 0; nt < 8; ++nt) {
      int col = wn * 128 + nt * 16 + ccol;
      float bb = bias[col];
#pragma unroll
      for (int reg = 0; reg < 4; ++reg) {
        int row = r0 + mt * 16 + crow + reg;
        if (row < M)
          out[(size_t)row * H_OUT + col] = fmaxf(acc[mt][nt][reg] + bb, 0.f);
      }
    }
  }
}

// ---------------------------------------------------------------------------
// Kernel 1: FUSED prep = histc | wprep | init (mutually independent).
// chist zeroed by hipMemsetAsync before this.
// ---------------------------------------------------------------------------
__global__ __launch_bounds__(256) void fused_prep(
    const float* __restrict__ x, const int* __restrict__ y,
    const int* __restrict__ batch0, const int* __restrict__ rows,
    const float* __restrict__ W0, const float* __restrict__ W1,
    ushort* __restrict__ xb, float* __restrict__ out,
    int* __restrict__ chist, ushort* __restrict__ Wf, int nconv4) {
  __shared__ int h[NB];
  int bid = blockIdx.x;
  int t = threadIdx.x;
  if (bid < NBIN) {                       // ---- histc ----
    for (int b = t; b < NB; b += 256) h[b] = 0;
    __syncthreads();
    int i0 = bid * RPB;
    for (int k = 0; k < RPB / 256; ++k) {
      int i = i0 + k * 256 + t;
      if (i < NNZ_CNT) atomicAdd(&h[rows[i] >> 7], 1);
    }
    __syncthreads();
    for (int b = t; b < NB; b += 256)
      if (h[b]) atomicAdd(&chist[b], h[b]);
  } else if (bid < NBIN + 32) {           // ---- wprep ----
    int idx = (bid - NBIN) * 256 + t;     // 0..8191
    const float* W = (idx & 4096) ? W1 : W0;
    int slot = idx & 4095;
    int nt = slot >> 8, ks = (slot >> 6) & 3, lane = slot & 63;
    int c  = nt * 16 + (lane & 15);
    int kb = ks * 32 + ((lane >> 4) << 3);
    short8 v;
#pragma unroll
    for (int j = 0; j < 8; ++j) v[j] = (short)f2b(W[(kb + j) * H_OUT + c]);
    ((short8*)Wf)[idx] = v;
  } else {                                // ---- init ----
    int i = (bid - NBIN - 32) * 256 + t;
    if (i < nconv4) {
      float4 v = ((const float4*)x)[i];
      ushort4 u;
      u.x = f2b(v.x); u.y = f2b(v.y); u.z = f2b(v.z); u.w = f2b(v.w);
      ((ushort4*)xb)[i] = u;
    }
    if (i < N_NODES) {
      out[i]           = (float)y[i];
      out[N_NODES + i] = (float)batch0[i];
    }
  }
}

// ---------------------------------------------------------------------------
// Kernel 2: scan of chist[NB] -> boff[NB+1], gtail[NB]; seed eoff tail.
// ---------------------------------------------------------------------------
__global__ __launch_bounds__(512) void scanc_kernel(
    const int* __restrict__ chist, int* __restrict__ boff,
    int* __restrict__ gtail, int* __restrict__ eoff) {
  __shared__ int s[512];
  int t = threadIdx.x;
  int v = (t < NB) ? chist[t] : 0;
  s[t] = v;
  __syncthreads();
  for (int d = 1; d < 512; d <<= 1) {
    int u = (t >= d) ? s[t - d] : 0;
    __syncthreads();
    s[t] += u;
    __syncthreads();
  }
  if (t < NB) {
    int ex = s[t] - v;
    boff[t]  = ex;
    gtail[t] = ex;
  }
  if (t == 0) { boff[NB] = NNZ_CNT; eoff[NB * BKT] = NNZ_CNT; }
}

// ---------------------------------------------------------------------------
// binpass body (verified r8): bucket-clustered records, rcache reg reuse.
// ---------------------------------------------------------------------------
__device__ __forceinline__ void binpass_body(
    const int* __restrict__ rows, const int* __restrict__ cols,
    const float* __restrict__ vals, int* __restrict__ gtail,
    uint2* __restrict__ buf, int* hist, int* rnk, int* base, int bid) {
  int rcache[RPB / 256];
  int t = threadIdx.x;
  for (int b = t; b < NB; b += 256) { hist[b] = 0; rnk[b] = 0; }
  __syncthreads();
  int i0 = bid * RPB;
#pragma unroll
  for (int k = 0; k < RPB / 256; ++k) {
    int i = i0 + k * 256 + t;
    int r = (i < NNZ_CNT) ? rows[i] : -1;
    rcache[k] = r;
    if (r >= 0) atomicAdd(&hist[r >> 7], 1);
  }
  __syncthreads();
  for (int b = t; b < NB; b += 256) {
    int c = hist[b];
    base[b] = c ? atomicAdd(&gtail[b], c) : 0;
  }
  __syncthreads();
#pragma unroll
  for (int k = 0; k < RPB / 256; ++k) {
    int r = rcache[k];
    if (r >= 0) {
      int i = i0 + k * 256 + t;
      int b = r >> 7;
      int pos = base[b] + atomicAdd(&rnk[b], 1);
      buf[pos] = make_uint2(((uint)(r & (BKT - 1)) << 17) | (uint)cols[i],
                            __float_as_uint(vals[i]));
    }
  }
}

// Kernel 3: binpass blocks + first GB_A gemm0 blocks (independent, overlap)
__global__ __launch_bounds__(256) void binpass_gemmA(
    const int* __restrict__ rows, const int* __restrict__ cols,
    const float* __restrict__ vals, int* __restrict__ gtail,
    uint2* __restrict__ buf, const ushort* __restrict__ xb,
    const ushort* __restrict__ Wf, const float* __restrict__ bias0,
    float* __restrict__ out0) {
  __shared__ int hist[NB], rnk[NB], base[NB];
  int bid = blockIdx.x;
  if (bid < NB)
    binpass_body(rows, cols, vals, gtail, buf, hist, rnk, base, bid);
  else
    gemm_body(xb, Wf, bias0, out0, N_NODES, bid - NB);
}

// ---------------------------------------------------------------------------
// finepass body (verified r8): per-bucket exact per-edge CSR; buf2 records
// hold pre-scaled byte offsets { col*256, bits(val) }.
// ---------------------------------------------------------------------------
__device__ __forceinline__ void finepass_body(
    const uint2* __restrict__ buf, const int* __restrict__ boff,
    uint2* __restrict__ buf2, int* __restrict__ eoff,
    int* lhist, int* lexc, int* lrnk, int b) {
  int t = threadIdx.x;
  if (t < BKT) { lhist[t] = 0; lrnk[t] = 0; }
  __syncthreads();
  int start = boff[b], end = boff[b + 1];
  for (int i = start + t; i < end; i += 256)
    atomicAdd(&lhist[buf[i].x >> 17], 1);
  __syncthreads();
  if (t < BKT) lexc[t] = lhist[t];
  __syncthreads();
  for (int d = 1; d < BKT; d <<= 1) {           // Hillis-Steele inclusive
    int v = (t < BKT && t >= d) ? lexc[t - d] : 0;
    __syncthreads();
    if (t < BKT) lexc[t] += v;
    __syncthreads();
  }
  if (t < BKT) {
    int ex = lexc[t] - lhist[t];                // -> exclusive
    lexc[t] = ex;
    eoff[b * BKT + t] = start + ex;
  }
  __syncthreads();
  for (int i = start + t; i < end; i += 256) {
    uint2 rec = buf[i];
    int rl = rec.x >> 17;
    int r = atomicAdd(&lrnk[rl], 1);
    buf2[start + lexc[rl] + r] =
        make_uint2((rec.x & 0x1FFFFu) << 8, rec.y);   // byte offset of row
  }
}

// Kernel 4: finepass blocks + remaining GB_B gemm0 blocks
__global__ __launch_bounds__(256) void finepass_gemmB(
    const uint2* __restrict__ buf, const int* __restrict__ boff,
    uint2* __restrict__ buf2, int* __restrict__ eoff,
    const ushort* __restrict__ xb, const ushort* __restrict__ Wf,
    const float* __restrict__ bias0, float* __restrict__ out0) {
  __shared__ int lhist[BKT], lexc[BKT], lrnk[BKT];
  int bid = blockIdx.x;
  if (bid < NB)
    finepass_body(buf, boff, buf2, eoff, lhist, lexc, lrnk, bid);
  else
    gemm_body(xb, Wf, bias0, out0, N_NODES, GB_A + (bid - NB));
}

// ---------------------------------------------------------------------------
// Kernel 5: per-edge gather-reduce (verified r8: staged LDS meta, full-width
// ushort2 lanes, 4-way unroll / 2 independent accumulator pairs).
// ---------------------------------------------------------------------------
__global__ __launch_bounds__(128) void edge_reduce(
    const ushort* __restrict__ xb, const uint2* __restrict__ buf2,
    const int* __restrict__ eoff, ushort* __restrict__ x1b) {
  __shared__ uint2 meta[128];
  __shared__ float pa[2][64], pb[2][64];
  int t = threadIdx.x, wave = t >> 6, lane = t & 63;
  int e = blockIdx.x;
  int start = eoff[e], end = eoff[e + 1];
  const char* xbase = (const char*)xb + 4 * lane;
  float s00 = 0.f, s01 = 0.f, s10 = 0.f, s11 = 0.f;
  for (int base = start; base < end; base += 128) {
    int m = min(128, end - base);
    if (t < m) meta[t] = buf2[base + t];
    __syncthreads();
    int j = wave;
    for (; j + 6 < m; j += 8) {
      uint2 r0 = meta[j], r1 = meta[j + 2], r2 = meta[j + 4], r3 = meta[j + 6];
      ushort2 v0 = *(const ushort2*)(xbase + r0.x);
      ushort2 v1 = *(const ushort2*)(xbase + r1.x);
      ushort2 v2 = *(const ushort2*)(xbase + r2.x);
      ushort2 v3 = *(const ushort2*)(xbase + r3.x);
      float w0 = __uint_as_float(r0.y), w1 = __uint_as_float(r1.y);
      float w2 = __uint_as_float(r2.y), w3 = __uint_as_float(r3.y);
      s00 = fmaf(b2f(v0.x), w0, s00); s01 = fmaf(b2f(v0.y), w0, s01);
      s10 = fmaf(b2f(v1.x), w1, s10); s11 = fmaf(b2f(v1.y), w1, s11);
      s00 = fmaf(b2f(v2.x), w2, s00); s01 = fmaf(b2f(v2.y), w2, s01);
      s10 = fmaf(b2f(v3.x), w3, s10); s11 = fmaf(b2f(v3.y), w3, s11);
    }
    for (; j < m; j += 2) {
      uint2 rec = meta[j];
      float w = __uint_as_float(rec.y);
      ushort2 xv = *(const ushort2*)(xbase + rec.x);
      s00 = fmaf(b2f(xv.x), w, s00);
      s01 = fmaf(b2f(xv.y), w, s01);
    }
    __syncthreads();
  }
  pa[wave][lane] = s00 + s10;   // semantic channel 2*lane
  pb[wave][lane] = s01 + s11;   // semantic channel 2*lane+1
  __syncthreads();
  if (t < 64) {
    uint lo = f2b(pa[0][t] + pa[1][t]);
    uint hi = f2b(pb[0][t] + pb[1][t]);
    ((uint*)x1b)[(size_t)e * 64 + t] = lo | (hi << 16);
  }
}

// ---------------------------------------------------------------------------
// Kernel 6: gemm for x1 (after edge_reduce; all x1b reads in their own
// dispatch — x1-side read/write fusion is unsafe, proven r10+r13)
// ---------------------------------------------------------------------------
__global__ __launch_bounds__(256) void gemm1_kernel(
    const ushort* __restrict__ A1, const ushort* __restrict__ Wf,
    const float* __restrict__ bias1, float* __restrict__ out1) {
  gemm_body(A1, Wf + 8 * 4096, bias1, out1, E_EDGES, blockIdx.x);
}

// ---------------------------------------------------------------------------
extern "C" void kernel_launch(void* const* d_in, const int* in_sizes, int n_in,
                              void* d_out, int out_size, void* d_ws, size_t ws_size,
                              hipStream_t stream) {
  const float* x        = (const float*)d_in[0];
  const int*   inc_rows = (const int*)d_in[1];
  const int*   inc_cols = (const int*)d_in[2];
  const float* inc_vals = (const float*)d_in[3];
  const int*   y        = (const int*)d_in[4];
  const int*   batch0   = (const int*)d_in[5];
  const float* W0       = (const float*)d_in[6];
  const float* b0       = (const float*)d_in[7];
  const float* W1       = (const float*)d_in[8];
  const float* b1       = (const float*)d_in[9];

  float* out = (float*)d_out;

  // ws: xb 25.6MB | x1b 12.8MB | buf 12.8MB | buf2 12.8MB | Wf 128KB |
  //     chist/boff/gtail ~5KB | eoff 200KB   (~65MB total)
  char* ws = (char*)d_ws;
  ushort* xb    = (ushort*)ws;  ws += (size_t)N_NODES * C_IN * 2;
  ushort* x1b   = (ushort*)ws;  ws += (size_t)E_EDGES * C_IN * 2;
  uint2*  buf   = (uint2*)ws;   ws += (size_t)NNZ_CNT * 8;
  uint2*  buf2  = (uint2*)ws;   ws += (size_t)NNZ_CNT * 8;
  ushort* Wf    = (ushort*)ws;  ws += (size_t)8192 * 8 * 2;
  int*    chist = (int*)ws;     ws += (size_t)NB * 4;
  int*    boff  = (int*)ws;     ws += (size_t)(NB + 1) * 4;
  int*    gtail = (int*)ws;     ws += (size_t)NB * 4;
  int*    eoff  = (int*)ws;     // NB*BKT+1 ints

  const int nconv4 = N_NODES * C_IN / 4;         // 3.2M
  const int ninit  = (nconv4 + 255) / 256;       // 12500
  const int nb1    = (E_EDGES + 63) / 64;        // 782

  float* x0_out = out + 2 * N_NODES;
  float* x1_out = out + 2 * N_NODES + (size_t)N_NODES * H_OUT;

  hipMemsetAsync(chist, 0, (size_t)NB * 4, stream);
  fused_prep<<<NBIN + 32 + ninit, 256, 0, stream>>>(
      x, y, batch0, inc_rows, W0, W1, xb, out, chist, Wf, nconv4);
  scanc_kernel<<<1, 512, 0, stream>>>(chist, boff, gtail, eoff);
  binpass_gemmA<<<NB + GB_A, 256, 0, stream>>>(
      inc_rows, inc_cols, inc_vals, gtail, buf, xb, Wf, b0, x0_out);
  finepass_gemmB<<<NB + GB_B, 256, 0, stream>>>(
      buf, boff, buf2, eoff, xb, Wf, b0, x0_out);
  edge_reduce<<<E_EDGES, 128, 0, stream>>>(xb, buf2, eoff, x1b);
  gemm1_kernel<<<nb1, 256, 0, stream>>>(x1b, Wf, b1, x1_out);
}